// Round 8
// baseline (447.821 us; speedup 1.0000x reference)
//
#include <hip/hip_runtime.h>

// GCN pull-mode, round 8: fused layer kernels. Every GEMM is row-local
// (Z[row] = dis*(t[row]@W)), so it runs in the aggregate's epilogue off
// LDS-resident rows; W (<=24 KB) read from global, L1-resident. 14->9
// dispatches, kills aggX/t1/t2/t3 streaming + their fp16 quant points.
//   megaA: agg64(xs) -> @W1+b1,relu -> @W2,*dis -> Z2 (fp16)
//   megaB: agg64(Z2)+b2,relu -> @W3,*dis -> Z3
//   megaC: agg32(Z3)+b3,relu -> @W4,*dis -> Z4
//   final: agg16(Z4)+b4 -> out (fp32)
// agg64 gather is at the random-line ceiling (~3.3 TB/s TCC fill) — unchanged.

#define TPB 256
#define NBUCK 782    // ceil(100000/128)
#define BCAP 3072    // max edges/bucket (avg 2047)
#define CHUNK 16384  // edges per block in phase C

typedef __attribute__((ext_vector_type(8))) _Float16 half8;
typedef __attribute__((ext_vector_type(4))) _Float16 half4;

// --- Phase A: coarse histogram ---
__global__ void bhist_kernel(const int* __restrict__ dst, int* __restrict__ bcnt, int E) {
    __shared__ int h[NBUCK];
    for (int i = threadIdx.x; i < NBUCK; i += blockDim.x) h[i] = 0;
    __syncthreads();
    for (int e = blockIdx.x * blockDim.x + threadIdx.x; e < E; e += gridDim.x * blockDim.x)
        atomicAdd(&h[dst[e] >> 7], 1);
    __syncthreads();
    for (int i = threadIdx.x; i < NBUCK; i += blockDim.x)
        if (h[i]) atomicAdd(&bcnt[i], h[i]);
}

// --- Phase B: scan 782 bucket counts ---
__global__ void bscan_kernel(const int* __restrict__ bcnt, int* __restrict__ bbase,
                             int* __restrict__ bcur) {
    __shared__ int ws[17];
    int tid = threadIdx.x;
    int lane = tid & 63, wid = tid >> 6;
    int v = (tid < NBUCK) ? bcnt[tid] : 0;
    int orig = v;
#pragma unroll
    for (int d = 1; d < 64; d <<= 1) {
        int u = __shfl_up(v, d, 64);
        if (lane >= d) v += u;
    }
    if (lane == 63) ws[wid] = v;
    __syncthreads();
    if (tid == 0) {
        int run = 0;
        for (int w = 0; w < 16; ++w) { int t = ws[w]; ws[w] = run; run += t; }
        ws[16] = run;
    }
    __syncthreads();
    int excl = ws[wid] + v - orig;
    if (tid < NBUCK) { bbase[tid] = excl; bcur[tid] = excl; }
    if (tid == 0) bbase[NBUCK] = ws[16];
}

// --- Phase C: scatter packed edges into bucket regions ---
__global__ void bscatter_kernel(const int* __restrict__ src, const int* __restrict__ dst,
                                int* __restrict__ bcur, int* __restrict__ bsort, int E) {
    __shared__ int h[NBUCK];
    __shared__ int cur[NBUCK];
    int tid = threadIdx.x;
    for (int i = tid; i < NBUCK; i += blockDim.x) h[i] = 0;
    __syncthreads();
    int base = blockIdx.x * CHUNK;
    int lim = min(base + CHUNK, E);
    for (int e = base + tid; e < lim; e += blockDim.x)
        atomicAdd(&h[dst[e] >> 7], 1);
    __syncthreads();
    for (int i = tid; i < NBUCK; i += blockDim.x)
        cur[i] = h[i] ? atomicAdd(&bcur[i], h[i]) : 0;
    __syncthreads();
    for (int e = base + tid; e < lim; e += blockDim.x) {
        int d = dst[e];
        int pos = atomicAdd(&cur[d >> 7], 1);
        bsort[pos] = ((d & 127) << 17) | src[e];  // src < 2^17
    }
}

// --- Phase D: per-bucket local sort -> csr/rowptr; dis; fused X prescale ---
__global__ __launch_bounds__(256) void bbuild_kernel(
        const int* __restrict__ bbase, const int* __restrict__ bsort,
        int* __restrict__ csr, int* __restrict__ rowptr, float* __restrict__ dis,
        const float4* __restrict__ x4, _Float16* __restrict__ xs,
        int N, int E) {
    __shared__ int ebuf[BCAP];
    __shared__ int obuf[BCAP];
    __shared__ int cnt[128];
    __shared__ int off[129];
    __shared__ float sdis[128];
    int b = blockIdx.x;
    int tid = threadIdx.x;
    int ebase = bbase[b];
    int n = min(bbase[b + 1] - ebase, BCAP);
    if (tid < 128) cnt[tid] = 0;
    __syncthreads();
    for (int i = tid; i < n; i += 256) {
        int p = bsort[ebase + i];
        ebuf[i] = p;
        atomicAdd(&cnt[p >> 17], 1);
    }
    __syncthreads();
    if (tid < 64) {
        int lane = tid;
        int v0 = cnt[lane];
#pragma unroll
        for (int d = 1; d < 64; d <<= 1) { int u = __shfl_up(v0, d, 64); if (lane >= d) v0 += u; }
        off[lane + 1] = v0;
        int tot0 = __shfl(v0, 63, 64);
        int v1 = cnt[64 + lane];
#pragma unroll
        for (int d = 1; d < 64; d <<= 1) { int u = __shfl_up(v1, d, 64); if (lane >= d) v1 += u; }
        off[64 + lane + 1] = tot0 + v1;
        if (lane == 0) off[0] = 0;
    }
    __syncthreads();
    int node0 = b << 7;
    if (tid < 128 && node0 + tid < N) {
        rowptr[node0 + tid] = ebase + off[tid];
        float d = rsqrtf((float)(off[tid + 1] - off[tid]) + 1.0f);
        dis[node0 + tid] = d;
        sdis[tid] = d;
    }
    if (b == (int)gridDim.x - 1 && tid == 128) rowptr[N] = E;
    if (tid < 128) cnt[tid] = off[tid];  // reuse as cursor
    __syncthreads();
    for (int i = tid; i < n; i += 256) {
        int p = ebuf[i];
        int pos = atomicAdd(&cnt[p >> 17], 1);
        obuf[pos] = p & 0x1FFFF;
    }
    __syncthreads();
    for (int i = tid; i < n; i += 256)
        csr[ebase + i] = obuf[i];
    // fused prescale: xs[node] = half(x[node] * dis[node]) for this bucket
    for (int i = tid; i < 128 * 16; i += 256) {
        int r = i >> 4, c = i & 15;
        int node = node0 + r;
        if (node >= N) break;
        float d = sdis[r];
        float4 v = x4[(size_t)node * 16 + c];
        half4 h;
        h[0] = (_Float16)(v.x * d); h[1] = (_Float16)(v.y * d);
        h[2] = (_Float16)(v.z * d); h[3] = (_Float16)(v.w * d);
        *(half4*)(xs + (size_t)node * 64 + 4 * c) = h;
    }
}

// Fused aggregate + row-local matvec chain.
// Agg (pull, fp16 gather, fp32 acc): u = dis*(sum_nbrs hs[s] + hs[row])
//   (+abias) (relu if ARELU)  -> LDS sAgg[RPB][F]
// Matvec1 (F->M1, Wx): acc (+xbias, relu if M1BR); if M2: -> LDS sT,
//   Matvec2 (M1->M2, Wy): *dis -> fp16 out.  Else: matvec1 *dis -> fp16 out.
// W/bias read from global (<=24 KB, L1-resident). Block = 4 waves, RPW rows
// per wave (RPB = 4*RPW rows per block).
template <int F, int RPW, bool ABIAS, bool ARELU, int M1, bool M1BR, int M2>
__global__ __launch_bounds__(256) void agg_fused_kernel(
        const _Float16* __restrict__ hs,
        const int* __restrict__ rowptr, const int* __restrict__ csr,
        const float* __restrict__ dis, const float* __restrict__ abias,
        const float* __restrict__ Wx, const float* __restrict__ xbias,
        const float* __restrict__ Wy,
        _Float16* __restrict__ outp, int N) {
    constexpr int RPB = 4 * RPW;    // rows per block
    constexpr int SPAN = 64 / RPW;  // lanes per row
    constexpr int LPR = F / 8;      // lanes per row-slice
    constexpr int G = SPAN / LPR;   // neighbor groups per row
    __shared__ float sAgg[RPB][F];
    __shared__ float sT[RPB][(M2 > 0) ? M1 : 1];

    int tid = threadIdx.x;
    int wr = tid >> 6;
    int lane = tid & 63;
    int srow = lane / SPAN;
    int l2 = lane % SPAN;
    int g = l2 / LPR;
    int q = l2 % LPR;
    int rbase = blockIdx.x * RPB;
    int br = wr * RPW + srow;
    int row = rbase + br;

    if (row < N) {
        int start = rowptr[row], end = rowptr[row + 1];
        float a0[8] = {}, a1[8] = {};
        if (g == 0) {  // self loop
            half8 v = *(const half8*)(hs + (size_t)row * F + 8 * q);
#pragma unroll
            for (int j = 0; j < 8; ++j) a0[j] = (float)v[j];
        }
        int e = start + g;
        for (; e + G < end; e += 2 * G) {
            int s0 = csr[e];
            int s1 = csr[e + G];
            half8 v0 = *(const half8*)(hs + (size_t)s0 * F + 8 * q);
            half8 v1 = *(const half8*)(hs + (size_t)s1 * F + 8 * q);
#pragma unroll
            for (int j = 0; j < 8; ++j) { a0[j] += (float)v0[j]; a1[j] += (float)v1[j]; }
        }
        for (; e < end; e += G) {
            int s = csr[e];
            half8 v = *(const half8*)(hs + (size_t)s * F + 8 * q);
#pragma unroll
            for (int j = 0; j < 8; ++j) a0[j] += (float)v[j];
        }
#pragma unroll
        for (int j = 0; j < 8; ++j) a0[j] += a1[j];
#pragma unroll
        for (int m = LPR; m < SPAN; m <<= 1) {
#pragma unroll
            for (int j = 0; j < 8; ++j) a0[j] += __shfl_xor(a0[j], m, 64);
        }
        if (g == 0) {
            float d = dis[row];
#pragma unroll
            for (int j = 0; j < 8; ++j) a0[j] *= d;
            if (ABIAS) {
#pragma unroll
                for (int j = 0; j < 8; ++j) a0[j] += abias[8 * q + j];
            }
            if (ARELU) {
#pragma unroll
                for (int j = 0; j < 8; ++j) a0[j] = fmaxf(a0[j], 0.f);
            }
#pragma unroll
            for (int j = 0; j < 8; ++j) sAgg[br][8 * q + j] = a0[j];
        }
    }
    __syncthreads();

    // matvec1: F -> M1
    for (int o = tid; o < RPB * M1; o += 256) {
        int r = o / M1, c = o % M1;
        if (rbase + r < N) {
            float acc = 0.f;
#pragma unroll 8
            for (int k = 0; k < F; ++k) acc += sAgg[r][k] * Wx[k * M1 + c];
            if (M1BR) acc = fmaxf(acc + xbias[c], 0.f);
            if (M2 > 0) {
                sT[r][c] = acc;
            } else {
                outp[(size_t)(rbase + r) * M1 + c] = (_Float16)(acc * dis[rbase + r]);
            }
        }
    }
    if (M2 > 0) {
        __syncthreads();
        // matvec2: M1 -> M2, *dis, fp16 store
        for (int o = tid; o < RPB * M2; o += 256) {
            int r = o / M2, c = o % M2;
            if (rbase + r < N) {
                float acc = 0.f;
#pragma unroll 8
                for (int k = 0; k < M1; ++k) acc += sT[r][k] * Wy[k * M2 + c];
                outp[(size_t)(rbase + r) * M2 + c] = (_Float16)(acc * dis[rbase + r]);
            }
        }
    }
}

// Final pull aggregation (F=16): out(fp32) = dis*(sum+self) + bias.
template <int F, int RPW, bool BIAS>
__global__ void aggregate_final_kernel(const _Float16* __restrict__ hs,
                                       const int* __restrict__ rowptr,
                                       const int* __restrict__ csr,
                                       const float* __restrict__ dis,
                                       const float* __restrict__ bias,
                                       float* __restrict__ outp, int N) {
    constexpr int SPAN = 64 / RPW;
    constexpr int LPR = F / 8;
    constexpr int G = SPAN / LPR;
    int wave = (blockIdx.x * blockDim.x + threadIdx.x) >> 6;
    int lane = threadIdx.x & 63;
    int srow = lane / SPAN;
    int l2 = lane % SPAN;
    int g = l2 / LPR;
    int q = l2 % LPR;
    int row = wave * RPW + srow;
    if (row >= N) return;
    int start = rowptr[row], end = rowptr[row + 1];
    float a0[8] = {}, a1[8] = {};
    if (g == 0) {
        half8 v = *(const half8*)(hs + (size_t)row * F + 8 * q);
#pragma unroll
        for (int j = 0; j < 8; ++j) a0[j] = (float)v[j];
    }
    int e = start + g;
    for (; e + G < end; e += 2 * G) {
        int s0 = csr[e];
        int s1 = csr[e + G];
        half8 v0 = *(const half8*)(hs + (size_t)s0 * F + 8 * q);
        half8 v1 = *(const half8*)(hs + (size_t)s1 * F + 8 * q);
#pragma unroll
        for (int j = 0; j < 8; ++j) { a0[j] += (float)v0[j]; a1[j] += (float)v1[j]; }
    }
    for (; e < end; e += G) {
        int s = csr[e];
        half8 v = *(const half8*)(hs + (size_t)s * F + 8 * q);
#pragma unroll
        for (int j = 0; j < 8; ++j) a0[j] += (float)v[j];
    }
#pragma unroll
    for (int j = 0; j < 8; ++j) a0[j] += a1[j];
#pragma unroll
    for (int m = LPR; m < SPAN; m <<= 1) {
#pragma unroll
        for (int j = 0; j < 8; ++j) a0[j] += __shfl_xor(a0[j], m, 64);
    }
    if (g == 0) {
        float d = dis[row];
#pragma unroll
        for (int j = 0; j < 8; ++j) a0[j] *= d;
        if (BIAS) {
            float4 bb0 = *(const float4*)(bias + 8 * q);
            float4 bb1 = *(const float4*)(bias + 8 * q + 4);
            a0[0] += bb0.x; a0[1] += bb0.y; a0[2] += bb0.z; a0[3] += bb0.w;
            a0[4] += bb1.x; a0[5] += bb1.y; a0[6] += bb1.z; a0[7] += bb1.w;
        }
        float4 o0 = {a0[0], a0[1], a0[2], a0[3]};
        float4 o1 = {a0[4], a0[5], a0[6], a0[7]};
        *(float4*)(outp + (size_t)row * F + 8 * q) = o0;
        *(float4*)(outp + (size_t)row * F + 8 * q + 4) = o1;
    }
}

static inline int cdiv(long long a, int b) { return (int)((a + b - 1) / b); }

extern "C" void kernel_launch(void* const* d_in, const int* in_sizes, int n_in,
                              void* d_out, int out_size, void* d_ws, size_t ws_size,
                              hipStream_t stream) {
    const float* x  = (const float*)d_in[0];
    const int*   ei = (const int*)d_in[1];
    const float* W1 = (const float*)d_in[2];
    const float* b1 = (const float*)d_in[3];
    const float* W2 = (const float*)d_in[4];
    const float* b2 = (const float*)d_in[5];
    const float* W3 = (const float*)d_in[6];
    const float* b3 = (const float*)d_in[7];
    const float* W4 = (const float*)d_in[8];
    const float* b4 = (const float*)d_in[9];
    float* out = (float*)d_out;

    const int N = in_sizes[0] / 64;   // 100000
    const int E = in_sizes[1] / 2;    // 1600000
    const int* src = ei;
    const int* dst = ei + E;

    int*   bcnt   = (int*)d_ws;             // 784
    int*   bbase  = bcnt + 784;             // 784 (need NBUCK+1)
    int*   bcur   = bbase + 784;            // 784
    int*   rowptr = bcur + 784;             // 100096
    int*   csr    = rowptr + 100096;        // E
    float* dis    = (float*)(csr + E);      // 100096
    _Float16* hP  = (_Float16*)(dis + 100096);   // N*64 halfs
    _Float16* hQ  = hP + (size_t)N * 64;         // N*64 halfs
    int*   bsort  = (int*)hP;               // E ints, aliased (dead before hP's first write)

    // --- CSR build (bucketed counting sort); dis + X-prescale in phase D ---
    hipMemsetAsync(bcnt, 0, 784 * sizeof(int), stream);
    bhist_kernel<<<256, TPB, 0, stream>>>(dst, bcnt, E);
    bscan_kernel<<<1, 1024, 0, stream>>>(bcnt, bbase, bcur);
    bscatter_kernel<<<cdiv(E, CHUNK), 512, 0, stream>>>(src, dst, bcur, bsort, E);
    bbuild_kernel<<<NBUCK, 256, 0, stream>>>(bbase, bsort, csr, rowptr, dis,
                                             (const float4*)x, hQ, N, E);

    // --- megaA: agg64(xs) -> @W1+b1,relu -> @W2,*dis -> Z2 (hP) ---
    agg_fused_kernel<64, 1, false, false, 96, true, 64><<<cdiv(N, 4), 256, 0, stream>>>(
        hQ, rowptr, csr, dis, nullptr, W1, b1, W2, hP, N);

    // --- megaB: agg64(Z2)+b2,relu -> @W3,*dis -> Z3 (hQ) ---
    agg_fused_kernel<64, 1, true, true, 32, false, 0><<<cdiv(N, 4), 256, 0, stream>>>(
        hP, rowptr, csr, dis, b2, W3, nullptr, nullptr, hQ, N);

    // --- megaC: agg32(Z3)+b3,relu -> @W4,*dis -> Z4 (hP) ---
    agg_fused_kernel<32, 2, true, true, 16, false, 0><<<cdiv(N, 8), 256, 0, stream>>>(
        hQ, rowptr, csr, dis, b3, W4, nullptr, nullptr, hP, N);

    // --- final: agg16(Z4)+b4 -> out (fp32) ---
    aggregate_final_kernel<16, 4, true><<<cdiv(N, 16), TPB, 0, stream>>>(
        hP, rowptr, csr, dis, b4, out, N);
}

// Round 9
// 348.669 us; speedup vs baseline: 1.2844x; 1.2844x over previous
//
#include <hip/hip_runtime.h>

// GCN pull-mode, round 9. Reverts r8's fused matvecs (2-load-per-FMA, VALU
// bound, +150us). Structure = r7 (separate agg + GEMM) but GEMMs use MFMA
// f16: one wave per 16-row strip, a-frags direct from global
// (A[m=lane&15][k=quad*8+j]), W pre-transposed to fp16 (b-frag
// B[n=lane&15][k=quad*8+j], L1-resident), C/D col=lane&15,row=quad*4+reg.
// csr reads in aggregates use nontemporal loads (less L2 pollution).
// agg64 gather pinned at random-line ceiling (~3.3 TB/s fill) — unchanged.

#define TPB 256
#define NBUCK 782    // ceil(100000/128)
#define BCAP 3072    // max edges/bucket (avg 2047)
#define CHUNK 16384  // edges per block in phase C

typedef __attribute__((ext_vector_type(8))) _Float16 half8;
typedef __attribute__((ext_vector_type(4))) _Float16 half4;
typedef __attribute__((ext_vector_type(4))) float f32x4;

// --- Phase A: coarse histogram ---
__global__ void bhist_kernel(const int* __restrict__ dst, int* __restrict__ bcnt, int E) {
    __shared__ int h[NBUCK];
    for (int i = threadIdx.x; i < NBUCK; i += blockDim.x) h[i] = 0;
    __syncthreads();
    for (int e = blockIdx.x * blockDim.x + threadIdx.x; e < E; e += gridDim.x * blockDim.x)
        atomicAdd(&h[dst[e] >> 7], 1);
    __syncthreads();
    for (int i = threadIdx.x; i < NBUCK; i += blockDim.x)
        if (h[i]) atomicAdd(&bcnt[i], h[i]);
}

// --- Phase B: scan 782 bucket counts ---
__global__ void bscan_kernel(const int* __restrict__ bcnt, int* __restrict__ bbase,
                             int* __restrict__ bcur) {
    __shared__ int ws[17];
    int tid = threadIdx.x;
    int lane = tid & 63, wid = tid >> 6;
    int v = (tid < NBUCK) ? bcnt[tid] : 0;
    int orig = v;
#pragma unroll
    for (int d = 1; d < 64; d <<= 1) {
        int u = __shfl_up(v, d, 64);
        if (lane >= d) v += u;
    }
    if (lane == 63) ws[wid] = v;
    __syncthreads();
    if (tid == 0) {
        int run = 0;
        for (int w = 0; w < 16; ++w) { int t = ws[w]; ws[w] = run; run += t; }
        ws[16] = run;
    }
    __syncthreads();
    int excl = ws[wid] + v - orig;
    if (tid < NBUCK) { bbase[tid] = excl; bcur[tid] = excl; }
    if (tid == 0) bbase[NBUCK] = ws[16];
}

// --- Phase C: scatter packed edges into bucket regions ---
__global__ void bscatter_kernel(const int* __restrict__ src, const int* __restrict__ dst,
                                int* __restrict__ bcur, int* __restrict__ bsort, int E) {
    __shared__ int h[NBUCK];
    __shared__ int cur[NBUCK];
    int tid = threadIdx.x;
    for (int i = tid; i < NBUCK; i += blockDim.x) h[i] = 0;
    __syncthreads();
    int base = blockIdx.x * CHUNK;
    int lim = min(base + CHUNK, E);
    for (int e = base + tid; e < lim; e += blockDim.x)
        atomicAdd(&h[dst[e] >> 7], 1);
    __syncthreads();
    for (int i = tid; i < NBUCK; i += blockDim.x)
        cur[i] = h[i] ? atomicAdd(&bcur[i], h[i]) : 0;
    __syncthreads();
    for (int e = base + tid; e < lim; e += blockDim.x) {
        int d = dst[e];
        int pos = atomicAdd(&cur[d >> 7], 1);
        bsort[pos] = ((d & 127) << 17) | src[e];  // src < 2^17
    }
}

// --- Phase D: per-bucket local sort -> csr/rowptr; dis; fused X prescale ---
__global__ __launch_bounds__(256) void bbuild_kernel(
        const int* __restrict__ bbase, const int* __restrict__ bsort,
        int* __restrict__ csr, int* __restrict__ rowptr, float* __restrict__ dis,
        const float4* __restrict__ x4, _Float16* __restrict__ xs,
        int N, int E) {
    __shared__ int ebuf[BCAP];
    __shared__ int obuf[BCAP];
    __shared__ int cnt[128];
    __shared__ int off[129];
    __shared__ float sdis[128];
    int b = blockIdx.x;
    int tid = threadIdx.x;
    int ebase = bbase[b];
    int n = min(bbase[b + 1] - ebase, BCAP);
    if (tid < 128) cnt[tid] = 0;
    __syncthreads();
    for (int i = tid; i < n; i += 256) {
        int p = bsort[ebase + i];
        ebuf[i] = p;
        atomicAdd(&cnt[p >> 17], 1);
    }
    __syncthreads();
    if (tid < 64) {
        int lane = tid;
        int v0 = cnt[lane];
#pragma unroll
        for (int d = 1; d < 64; d <<= 1) { int u = __shfl_up(v0, d, 64); if (lane >= d) v0 += u; }
        off[lane + 1] = v0;
        int tot0 = __shfl(v0, 63, 64);
        int v1 = cnt[64 + lane];
#pragma unroll
        for (int d = 1; d < 64; d <<= 1) { int u = __shfl_up(v1, d, 64); if (lane >= d) v1 += u; }
        off[64 + lane + 1] = tot0 + v1;
        if (lane == 0) off[0] = 0;
    }
    __syncthreads();
    int node0 = b << 7;
    if (tid < 128 && node0 + tid < N) {
        rowptr[node0 + tid] = ebase + off[tid];
        float d = rsqrtf((float)(off[tid + 1] - off[tid]) + 1.0f);
        dis[node0 + tid] = d;
        sdis[tid] = d;
    }
    if (b == (int)gridDim.x - 1 && tid == 128) rowptr[N] = E;
    if (tid < 128) cnt[tid] = off[tid];  // reuse as cursor
    __syncthreads();
    for (int i = tid; i < n; i += 256) {
        int p = ebuf[i];
        int pos = atomicAdd(&cnt[p >> 17], 1);
        obuf[pos] = p & 0x1FFFF;
    }
    __syncthreads();
    for (int i = tid; i < n; i += 256)
        csr[ebase + i] = obuf[i];
    // fused prescale: xs[node] = half(x[node] * dis[node]) for this bucket
    for (int i = tid; i < 128 * 16; i += 256) {
        int r = i >> 4, c = i & 15;
        int node = node0 + r;
        if (node >= N) break;
        float d = sdis[r];
        float4 v = x4[(size_t)node * 16 + c];
        half4 h;
        h[0] = (_Float16)(v.x * d); h[1] = (_Float16)(v.y * d);
        h[2] = (_Float16)(v.z * d); h[3] = (_Float16)(v.w * d);
        *(half4*)(xs + (size_t)node * 64 + 4 * c) = h;
    }
}

// Transpose + fp16-convert all weight matrices: Wt[m*K+k] = half(W[k*M+m]).
// Sections: W1t 96x64 @0, W2t 64x96 @6144, W3t 32x64 @12288, W4t 16x32 @14336.
__global__ void wprep_kernel(const float* __restrict__ W1, const float* __restrict__ W2,
                             const float* __restrict__ W3, const float* __restrict__ W4,
                             _Float16* __restrict__ wt) {
    int t = blockIdx.x * blockDim.x + threadIdx.x;
    if (t < 6144) {
        int m = t / 64, k = t % 64;
        wt[t] = (_Float16)W1[k * 96 + m];
    } else if (t < 12288) {
        int i = t - 6144; int m = i / 96, k = i % 96;
        wt[t] = (_Float16)W2[k * 64 + m];
    } else if (t < 14336) {
        int i = t - 12288; int m = i / 64, k = i % 64;
        wt[t] = (_Float16)W3[k * 32 + m];
    } else if (t < 14848) {
        int i = t - 14336; int m = i / 32, k = i % 32;
        wt[t] = (_Float16)W4[k * 16 + m];
    }
}

// MFMA f16 GEMM: out[N,MF] fp16 = X[N,K] fp16 @ W (+bias,relu | *dis).
// One wave per 16-row strip; a-frags loaded once from global
// (A[m=lane&15][k=quad*8+j]); loops MF/16 col tiles, b-frag from Wt
// (B[n=lane&15][k=quad*8+j], Wt is MFxK row-major fp16, L1-resident).
// C/D: col=lane&15, row=quad*4+reg (m89-verified, dtype-independent).
template <int K, int MF, bool RELU, bool BIAS, bool DIS>
__global__ __launch_bounds__(256) void gemm_mfma_kernel(
        const _Float16* __restrict__ X, const _Float16* __restrict__ Wt,
        const float* __restrict__ bias, const float* __restrict__ dis,
        _Float16* __restrict__ outp, int N) {
    constexpr int KT = K / 32;   // k tiles
    constexpr int CT = MF / 16;  // col tiles
    int wave = (blockIdx.x * blockDim.x + threadIdx.x) >> 6;
    int lane = threadIdx.x & 63;
    int quad = lane >> 4;
    int m16 = lane & 15;
    int rbase = wave * 16;
    if (rbase >= N) return;
    int arow = rbase + m16;

    half8 a[KT];
    if (arow < N) {
#pragma unroll
        for (int kt = 0; kt < KT; ++kt)
            a[kt] = *(const half8*)(X + (size_t)arow * K + kt * 32 + quad * 8);
    } else {
#pragma unroll
        for (int kt = 0; kt < KT; ++kt) {
#pragma unroll
            for (int j = 0; j < 8; ++j) a[kt][j] = (_Float16)0.f;
        }
    }
    float dvals[4];
    if (DIS) {
#pragma unroll
        for (int r = 0; r < 4; ++r) {
            int orow = rbase + quad * 4 + r;
            dvals[r] = (orow < N) ? dis[orow] : 0.f;
        }
    }
#pragma unroll
    for (int ct = 0; ct < CT; ++ct) {
        f32x4 c = {0.f, 0.f, 0.f, 0.f};
#pragma unroll
        for (int kt = 0; kt < KT; ++kt) {
            half8 b = *(const half8*)(Wt + (size_t)(ct * 16 + m16) * K + kt * 32 + quad * 8);
            c = __builtin_amdgcn_mfma_f32_16x16x32_f16(a[kt], b, c, 0, 0, 0);
        }
        int col = ct * 16 + m16;
        float bb = BIAS ? bias[col] : 0.f;
#pragma unroll
        for (int r = 0; r < 4; ++r) {
            int orow = rbase + quad * 4 + r;
            if (orow < N) {
                float v = c[r] + bb;
                if (RELU) v = fmaxf(v, 0.f);
                if (DIS) v *= dvals[r];
                outp[(size_t)orow * MF + col] = (_Float16)v;
            }
        }
    }
}

// Pull aggregation over fp16 messages. RPW rows per wave; per row G = SPAN/LPR
// neighbor groups each gathering a half8 (16 B) slice; 2x unroll; fp32
// accumulate; shfl_xor reduce within the row's SPAN-lane segment.
template <int F, int RPW, bool BIAS, bool RELU, bool OUTH>
__global__ void aggregate_f16_kernel(const _Float16* __restrict__ hs,
                                     const int* __restrict__ rowptr,
                                     const int* __restrict__ csr,
                                     const float* __restrict__ dis,
                                     const float* __restrict__ bias,
                                     void* __restrict__ outp, int N) {
    constexpr int SPAN = 64 / RPW;  // lanes per row
    constexpr int LPR = F / 8;      // lanes per row-slice
    constexpr int G = SPAN / LPR;   // neighbor groups per row
    int wave = (blockIdx.x * blockDim.x + threadIdx.x) >> 6;
    int lane = threadIdx.x & 63;
    int srow = lane / SPAN;
    int l2 = lane % SPAN;
    int g = l2 / LPR;
    int q = l2 % LPR;
    int row = wave * RPW + srow;
    if (row >= N) return;
    int start = rowptr[row], end = rowptr[row + 1];
    float a0[8] = {}, a1[8] = {};
    if (g == 0) {  // self loop
        half8 v = *(const half8*)(hs + (size_t)row * F + 8 * q);
#pragma unroll
        for (int j = 0; j < 8; ++j) a0[j] = (float)v[j];
    }
    int e = start + g;
    for (; e + G < end; e += 2 * G) {
        int s0 = __builtin_nontemporal_load(csr + e);
        int s1 = __builtin_nontemporal_load(csr + e + G);
        half8 v0 = *(const half8*)(hs + (size_t)s0 * F + 8 * q);
        half8 v1 = *(const half8*)(hs + (size_t)s1 * F + 8 * q);
#pragma unroll
        for (int j = 0; j < 8; ++j) { a0[j] += (float)v0[j]; a1[j] += (float)v1[j]; }
    }
    for (; e < end; e += G) {
        int s = __builtin_nontemporal_load(csr + e);
        half8 v = *(const half8*)(hs + (size_t)s * F + 8 * q);
#pragma unroll
        for (int j = 0; j < 8; ++j) a0[j] += (float)v[j];
    }
#pragma unroll
    for (int j = 0; j < 8; ++j) a0[j] += a1[j];
#pragma unroll
    for (int m = LPR; m < SPAN; m <<= 1) {
#pragma unroll
        for (int j = 0; j < 8; ++j) a0[j] += __shfl_xor(a0[j], m, 64);
    }
    if (g == 0) {
        float d = dis[row];
#pragma unroll
        for (int j = 0; j < 8; ++j) a0[j] *= d;
        if (BIAS) {
#pragma unroll
            for (int j = 0; j < 8; ++j) a0[j] += bias[8 * q + j];
        }
        if (RELU) {
#pragma unroll
            for (int j = 0; j < 8; ++j) a0[j] = fmaxf(a0[j], 0.f);
        }
        if (OUTH) {
            half8 h;
#pragma unroll
            for (int j = 0; j < 8; ++j) h[j] = (_Float16)a0[j];
            *(half8*)((_Float16*)outp + (size_t)row * F + 8 * q) = h;
        } else {
            float4 o0 = {a0[0], a0[1], a0[2], a0[3]};
            float4 o1 = {a0[4], a0[5], a0[6], a0[7]};
            *(float4*)((float*)outp + (size_t)row * F + 8 * q) = o0;
            *(float4*)((float*)outp + (size_t)row * F + 8 * q + 4) = o1;
        }
    }
}

static inline int cdiv(long long a, int b) { return (int)((a + b - 1) / b); }

extern "C" void kernel_launch(void* const* d_in, const int* in_sizes, int n_in,
                              void* d_out, int out_size, void* d_ws, size_t ws_size,
                              hipStream_t stream) {
    const float* x  = (const float*)d_in[0];
    const int*   ei = (const int*)d_in[1];
    const float* W1 = (const float*)d_in[2];
    const float* b1 = (const float*)d_in[3];
    const float* W2 = (const float*)d_in[4];
    const float* b2 = (const float*)d_in[5];
    const float* W3 = (const float*)d_in[6];
    const float* b3 = (const float*)d_in[7];
    const float* W4 = (const float*)d_in[8];
    const float* b4 = (const float*)d_in[9];
    float* out = (float*)d_out;

    const int N = in_sizes[0] / 64;   // 100000
    const int E = in_sizes[1] / 2;    // 1600000
    const int* src = ei;
    const int* dst = ei + E;

    int*   bcnt   = (int*)d_ws;             // 784
    int*   bbase  = bcnt + 784;             // 784 (need NBUCK+1)
    int*   bcur   = bbase + 784;            // 784
    int*   rowptr = bcur + 784;             // 100096
    int*   csr    = rowptr + 100096;        // E
    float* dis    = (float*)(csr + E);      // 100096
    _Float16* hP  = (_Float16*)(dis + 100096);   // N*64 halfs
    _Float16* hQ  = hP + (size_t)N * 64;         // N*64 halfs
    _Float16* hR  = hQ + (size_t)N * 64;         // N*96 halfs
    _Float16* wt  = hR + (size_t)N * 96;         // 14848 halfs (Wt fp16)
    int*   bsort  = (int*)hP;               // E ints, aliased (dead before hP's first write)

    // --- CSR build (bucketed counting sort); dis + X-prescale in phase D ---
    hipMemsetAsync(bcnt, 0, 784 * sizeof(int), stream);
    wprep_kernel<<<cdiv(14848, TPB), TPB, 0, stream>>>(W1, W2, W3, W4, wt);
    bhist_kernel<<<256, TPB, 0, stream>>>(dst, bcnt, E);
    bscan_kernel<<<1, 1024, 0, stream>>>(bcnt, bbase, bcur);
    bscatter_kernel<<<cdiv(E, CHUNK), 512, 0, stream>>>(src, dst, bcur, bsort, E);
    bbuild_kernel<<<NBUCK, 256, 0, stream>>>(bbase, bsort, csr, rowptr, dis,
                                             (const float4*)x, hQ, N, E);

    // --- Layer 1: hP = agg64(hQ=half(x*dis)); hR = half(relu(hP@W1+b1)) ---
    aggregate_f16_kernel<64, 1, false, false, true><<<cdiv(N, 4), TPB, 0, stream>>>(
        hQ, rowptr, csr, dis, nullptr, hP, N);
    gemm_mfma_kernel<64, 96, true, true, false><<<cdiv(N, 64), 256, 0, stream>>>(
        hP, wt + 0, b1, nullptr, hR, N);                              // hR = t1

    // --- Layer 2: hP = half(dis*(t1@W2)); hQ = half(relu(agg64(hP)+b2)) ---
    gemm_mfma_kernel<96, 64, false, false, true><<<cdiv(N, 64), 256, 0, stream>>>(
        hR, wt + 6144, nullptr, dis, hP, N);                          // hP = Z2
    aggregate_f16_kernel<64, 1, true, true, true><<<cdiv(N, 4), TPB, 0, stream>>>(
        hP, rowptr, csr, dis, b2, hQ, N);                             // hQ = t2

    // --- Layer 3: hP = half(dis*(t2@W3)); hQ = half(relu(agg32(hP)+b3)) ---
    gemm_mfma_kernel<64, 32, false, false, true><<<cdiv(N, 64), 256, 0, stream>>>(
        hQ, wt + 12288, nullptr, dis, hP, N);                         // hP = Z3
    aggregate_f16_kernel<32, 2, true, true, true><<<cdiv(N, 8), TPB, 0, stream>>>(
        hP, rowptr, csr, dis, b3, hQ, N);                             // hQ = t3

    // --- Layer 4: hP = half(dis*(t3@W4)); out = agg16(hP)+b4 (fp32) ---
    gemm_mfma_kernel<32, 16, false, false, true><<<cdiv(N, 64), 256, 0, stream>>>(
        hQ, wt + 14336, nullptr, dis, hP, N);                         // hP = Z4
    aggregate_f16_kernel<16, 4, true, false, false><<<cdiv(N, 16), TPB, 0, stream>>>(
        hP, rowptr, csr, dis, b4, out, N);
}

// Round 10
// 321.580 us; speedup vs baseline: 1.3926x; 1.0842x over previous
//
#include <hip/hip_runtime.h>

// GCN pull-mode, round 10.
// - Revert r9's nontemporal csr loads (cost +4us/agg64: evicted broadcast-
//   reused csr lines).
// - Scan-free CSR build: each 128-node bucket owns a FIXED slot of BCAP
//   edges (b*BCAP). Kills bhist + bscan entirely; bscatter reserves from
//   zeroed cursors; bbuild emits per-row (rowstart, rowdeg) computed locally.
//   Aggregates read rowstart/rowdeg (same load count as rowptr pairs).
// - MFMA f16 GEMMs (r9), agg64 at random-line fill ceiling (~3.3 TB/s).

#define TPB 256
#define NBUCK 782    // ceil(100000/128)
#define BCAP 3072    // fixed slot size; mean 2047, +22 sigma headroom
#define CHUNK 8192   // edges per block in scatter

typedef __attribute__((ext_vector_type(8))) _Float16 half8;
typedef __attribute__((ext_vector_type(4))) _Float16 half4;
typedef __attribute__((ext_vector_type(4))) float f32x4;

// --- Scatter packed edges into fixed bucket slots (no scan needed) ---
__global__ void bscatter_kernel(const int* __restrict__ src, const int* __restrict__ dst,
                                int* __restrict__ bcur, int* __restrict__ bsort, int E) {
    __shared__ int h[NBUCK];
    __shared__ int cur[NBUCK];
    int tid = threadIdx.x;
    for (int i = tid; i < NBUCK; i += blockDim.x) h[i] = 0;
    __syncthreads();
    int base = blockIdx.x * CHUNK;
    int lim = min(base + CHUNK, E);
    for (int e = base + tid; e < lim; e += blockDim.x)
        atomicAdd(&h[dst[e] >> 7], 1);
    __syncthreads();
    for (int i = tid; i < NBUCK; i += blockDim.x)
        cur[i] = h[i] ? ((size_t)0, atomicAdd(&bcur[i], h[i]) + i * BCAP) : 0;
    __syncthreads();
    for (int e = base + tid; e < lim; e += blockDim.x) {
        int d = dst[e];
        int pos = atomicAdd(&cur[d >> 7], 1);
        bsort[pos] = ((d & 127) << 17) | src[e];  // src < 2^17
    }
}

// --- Per-bucket local sort -> csr slot; rowstart/rowdeg/dis; X prescale ---
__global__ __launch_bounds__(256) void bbuild_kernel(
        const int* __restrict__ bcur, const int* __restrict__ bsort,
        int* __restrict__ csr, int* __restrict__ rowstart, int* __restrict__ rowdeg,
        float* __restrict__ dis,
        const float4* __restrict__ x4, _Float16* __restrict__ xs,
        int N) {
    __shared__ int ebuf[BCAP];
    __shared__ int obuf[BCAP];
    __shared__ int cnt[128];
    __shared__ int off[129];
    __shared__ float sdis[128];
    int b = blockIdx.x;
    int tid = threadIdx.x;
    int ebase = b * BCAP;
    int n = min(bcur[b], BCAP);
    if (tid < 128) cnt[tid] = 0;
    __syncthreads();
    for (int i = tid; i < n; i += 256) {
        int p = bsort[ebase + i];
        ebuf[i] = p;
        atomicAdd(&cnt[p >> 17], 1);
    }
    __syncthreads();
    if (tid < 64) {
        int lane = tid;
        int v0 = cnt[lane];
#pragma unroll
        for (int d = 1; d < 64; d <<= 1) { int u = __shfl_up(v0, d, 64); if (lane >= d) v0 += u; }
        off[lane + 1] = v0;
        int tot0 = __shfl(v0, 63, 64);
        int v1 = cnt[64 + lane];
#pragma unroll
        for (int d = 1; d < 64; d <<= 1) { int u = __shfl_up(v1, d, 64); if (lane >= d) v1 += u; }
        off[64 + lane + 1] = tot0 + v1;
        if (lane == 0) off[0] = 0;
    }
    __syncthreads();
    int node0 = b << 7;
    if (tid < 128 && node0 + tid < N) {
        int deg = off[tid + 1] - off[tid];
        rowstart[node0 + tid] = ebase + off[tid];
        rowdeg[node0 + tid] = deg;
        float d = rsqrtf((float)deg + 1.0f);
        dis[node0 + tid] = d;
        sdis[tid] = d;
    }
    if (tid < 128) cnt[tid] = off[tid];  // reuse as cursor
    __syncthreads();
    for (int i = tid; i < n; i += 256) {
        int p = ebuf[i];
        int pos = atomicAdd(&cnt[p >> 17], 1);
        obuf[pos] = p & 0x1FFFF;
    }
    __syncthreads();
    for (int i = tid; i < n; i += 256)
        csr[ebase + i] = obuf[i];
    // fused prescale: xs[node] = half(x[node] * dis[node]) for this bucket
    for (int i = tid; i < 128 * 16; i += 256) {
        int r = i >> 4, c = i & 15;
        int node = node0 + r;
        if (node >= N) break;
        float d = sdis[r];
        float4 v = x4[(size_t)node * 16 + c];
        half4 h;
        h[0] = (_Float16)(v.x * d); h[1] = (_Float16)(v.y * d);
        h[2] = (_Float16)(v.z * d); h[3] = (_Float16)(v.w * d);
        *(half4*)(xs + (size_t)node * 64 + 4 * c) = h;
    }
}

// Transpose + fp16-convert all weight matrices: Wt[m*K+k] = half(W[k*M+m]).
// Sections: W1t 96x64 @0, W2t 64x96 @6144, W3t 32x64 @12288, W4t 16x32 @14336.
__global__ void wprep_kernel(const float* __restrict__ W1, const float* __restrict__ W2,
                             const float* __restrict__ W3, const float* __restrict__ W4,
                             _Float16* __restrict__ wt) {
    int t = blockIdx.x * blockDim.x + threadIdx.x;
    if (t < 6144) {
        int m = t / 64, k = t % 64;
        wt[t] = (_Float16)W1[k * 96 + m];
    } else if (t < 12288) {
        int i = t - 6144; int m = i / 96, k = i % 96;
        wt[t] = (_Float16)W2[k * 64 + m];
    } else if (t < 14336) {
        int i = t - 12288; int m = i / 64, k = i % 64;
        wt[t] = (_Float16)W3[k * 32 + m];
    } else if (t < 14848) {
        int i = t - 14336; int m = i / 32, k = i % 32;
        wt[t] = (_Float16)W4[k * 16 + m];
    }
}

// MFMA f16 GEMM: out[N,MF] fp16 = X[N,K] fp16 @ W (+bias,relu | *dis).
// One wave per 16-row strip; a-frags A[m=lane&15][k=quad*8+j] from global;
// b-frag from Wt (MFxK row-major fp16, L1-resident);
// C/D: col=lane&15, row=quad*4+reg.
template <int K, int MF, bool RELU, bool BIAS, bool DIS>
__global__ __launch_bounds__(256) void gemm_mfma_kernel(
        const _Float16* __restrict__ X, const _Float16* __restrict__ Wt,
        const float* __restrict__ bias, const float* __restrict__ dis,
        _Float16* __restrict__ outp, int N) {
    constexpr int KT = K / 32;   // k tiles
    constexpr int CT = MF / 16;  // col tiles
    int wave = (blockIdx.x * blockDim.x + threadIdx.x) >> 6;
    int lane = threadIdx.x & 63;
    int quad = lane >> 4;
    int m16 = lane & 15;
    int rbase = wave * 16;
    if (rbase >= N) return;
    int arow = rbase + m16;

    half8 a[KT];
    if (arow < N) {
#pragma unroll
        for (int kt = 0; kt < KT; ++kt)
            a[kt] = *(const half8*)(X + (size_t)arow * K + kt * 32 + quad * 8);
    } else {
#pragma unroll
        for (int kt = 0; kt < KT; ++kt) {
#pragma unroll
            for (int j = 0; j < 8; ++j) a[kt][j] = (_Float16)0.f;
        }
    }
    float dvals[4];
    if (DIS) {
#pragma unroll
        for (int r = 0; r < 4; ++r) {
            int orow = rbase + quad * 4 + r;
            dvals[r] = (orow < N) ? dis[orow] : 0.f;
        }
    }
#pragma unroll
    for (int ct = 0; ct < CT; ++ct) {
        f32x4 c = {0.f, 0.f, 0.f, 0.f};
#pragma unroll
        for (int kt = 0; kt < KT; ++kt) {
            half8 b = *(const half8*)(Wt + (size_t)(ct * 16 + m16) * K + kt * 32 + quad * 8);
            c = __builtin_amdgcn_mfma_f32_16x16x32_f16(a[kt], b, c, 0, 0, 0);
        }
        int col = ct * 16 + m16;
        float bb = BIAS ? bias[col] : 0.f;
#pragma unroll
        for (int r = 0; r < 4; ++r) {
            int orow = rbase + quad * 4 + r;
            if (orow < N) {
                float v = c[r] + bb;
                if (RELU) v = fmaxf(v, 0.f);
                if (DIS) v *= dvals[r];
                outp[(size_t)orow * MF + col] = (_Float16)v;
            }
        }
    }
}

// Pull aggregation over fp16 messages. RPW rows per wave; per row G = SPAN/LPR
// neighbor groups each gathering a half8 (16 B) slice; 2x unroll; fp32
// accumulate; shfl_xor reduce within the row's SPAN-lane segment.
template <int F, int RPW, bool BIAS, bool RELU, bool OUTH>
__global__ void aggregate_f16_kernel(const _Float16* __restrict__ hs,
                                     const int* __restrict__ rowstart,
                                     const int* __restrict__ rowdeg,
                                     const int* __restrict__ csr,
                                     const float* __restrict__ dis,
                                     const float* __restrict__ bias,
                                     void* __restrict__ outp, int N) {
    constexpr int SPAN = 64 / RPW;  // lanes per row
    constexpr int LPR = F / 8;      // lanes per row-slice
    constexpr int G = SPAN / LPR;   // neighbor groups per row
    int wave = (blockIdx.x * blockDim.x + threadIdx.x) >> 6;
    int lane = threadIdx.x & 63;
    int srow = lane / SPAN;
    int l2 = lane % SPAN;
    int g = l2 / LPR;
    int q = l2 % LPR;
    int row = wave * RPW + srow;
    if (row >= N) return;
    int start = rowstart[row];
    int end = start + rowdeg[row];
    float a0[8] = {}, a1[8] = {};
    if (g == 0) {  // self loop
        half8 v = *(const half8*)(hs + (size_t)row * F + 8 * q);
#pragma unroll
        for (int j = 0; j < 8; ++j) a0[j] = (float)v[j];
    }
    int e = start + g;
    for (; e + G < end; e += 2 * G) {
        int s0 = csr[e];
        int s1 = csr[e + G];
        half8 v0 = *(const half8*)(hs + (size_t)s0 * F + 8 * q);
        half8 v1 = *(const half8*)(hs + (size_t)s1 * F + 8 * q);
#pragma unroll
        for (int j = 0; j < 8; ++j) { a0[j] += (float)v0[j]; a1[j] += (float)v1[j]; }
    }
    for (; e < end; e += G) {
        int s = csr[e];
        half8 v = *(const half8*)(hs + (size_t)s * F + 8 * q);
#pragma unroll
        for (int j = 0; j < 8; ++j) a0[j] += (float)v[j];
    }
#pragma unroll
    for (int j = 0; j < 8; ++j) a0[j] += a1[j];
#pragma unroll
    for (int m = LPR; m < SPAN; m <<= 1) {
#pragma unroll
        for (int j = 0; j < 8; ++j) a0[j] += __shfl_xor(a0[j], m, 64);
    }
    if (g == 0) {
        float d = dis[row];
#pragma unroll
        for (int j = 0; j < 8; ++j) a0[j] *= d;
        if (BIAS) {
#pragma unroll
            for (int j = 0; j < 8; ++j) a0[j] += bias[8 * q + j];
        }
        if (RELU) {
#pragma unroll
            for (int j = 0; j < 8; ++j) a0[j] = fmaxf(a0[j], 0.f);
        }
        if (OUTH) {
            half8 h;
#pragma unroll
            for (int j = 0; j < 8; ++j) h[j] = (_Float16)a0[j];
            *(half8*)((_Float16*)outp + (size_t)row * F + 8 * q) = h;
        } else {
            float4 o0 = {a0[0], a0[1], a0[2], a0[3]};
            float4 o1 = {a0[4], a0[5], a0[6], a0[7]};
            *(float4*)((float*)outp + (size_t)row * F + 8 * q) = o0;
            *(float4*)((float*)outp + (size_t)row * F + 8 * q + 4) = o1;
        }
    }
}

static inline int cdiv(long long a, int b) { return (int)((a + b - 1) / b); }

extern "C" void kernel_launch(void* const* d_in, const int* in_sizes, int n_in,
                              void* d_out, int out_size, void* d_ws, size_t ws_size,
                              hipStream_t stream) {
    const float* x  = (const float*)d_in[0];
    const int*   ei = (const int*)d_in[1];
    const float* W1 = (const float*)d_in[2];
    const float* b1 = (const float*)d_in[3];
    const float* W2 = (const float*)d_in[4];
    const float* b2 = (const float*)d_in[5];
    const float* W3 = (const float*)d_in[6];
    const float* b3 = (const float*)d_in[7];
    const float* W4 = (const float*)d_in[8];
    const float* b4 = (const float*)d_in[9];
    float* out = (float*)d_out;

    const int N = in_sizes[0] / 64;   // 100000
    const int E = in_sizes[1] / 2;    // 1600000
    const int* src = ei;
    const int* dst = ei + E;

    int*   bcur     = (int*)d_ws;                 // 788
    int*   rowstart = bcur + 788;                 // 100096
    int*   rowdeg   = rowstart + 100096;          // 100096
    int*   csr      = rowdeg + 100096;            // NBUCK*BCAP (padded slots)
    float* dis      = (float*)(csr + NBUCK * BCAP);  // 100096
    _Float16* hP    = (_Float16*)(dis + 100096);  // N*64 halfs
    _Float16* hQ    = hP + (size_t)N * 64;        // N*64 halfs
    _Float16* hR    = hQ + (size_t)N * 64;        // N*96 halfs
    _Float16* wt    = hR + (size_t)N * 96;        // 14848 halfs (Wt fp16)
    int*   bsort    = (int*)hP;  // NBUCK*BCAP ints (9.6 MB <= hP 12.8 MB), dead before hP write

    // --- build: zero cursors; scatter into fixed slots; per-bucket sort ---
    hipMemsetAsync(bcur, 0, 788 * sizeof(int), stream);
    wprep_kernel<<<cdiv(14848, TPB), TPB, 0, stream>>>(W1, W2, W3, W4, wt);
    bscatter_kernel<<<cdiv(E, CHUNK), 512, 0, stream>>>(src, dst, bcur, bsort, E);
    bbuild_kernel<<<NBUCK, 256, 0, stream>>>(bcur, bsort, csr, rowstart, rowdeg, dis,
                                             (const float4*)x, hQ, N);

    // --- Layer 1: hP = agg64(hQ=half(x*dis)); hR = half(relu(hP@W1+b1)) ---
    aggregate_f16_kernel<64, 1, false, false, true><<<cdiv(N, 4), TPB, 0, stream>>>(
        hQ, rowstart, rowdeg, csr, dis, nullptr, hP, N);
    gemm_mfma_kernel<64, 96, true, true, false><<<cdiv(N, 64), 256, 0, stream>>>(
        hP, wt + 0, b1, nullptr, hR, N);                              // hR = t1

    // --- Layer 2: hP = half(dis*(t1@W2)); hQ = half(relu(agg64(hP)+b2)) ---
    gemm_mfma_kernel<96, 64, false, false, true><<<cdiv(N, 64), 256, 0, stream>>>(
        hR, wt + 6144, nullptr, dis, hP, N);                          // hP = Z2
    aggregate_f16_kernel<64, 1, true, true, true><<<cdiv(N, 4), TPB, 0, stream>>>(
        hP, rowstart, rowdeg, csr, dis, b2, hQ, N);                   // hQ = t2

    // --- Layer 3: hP = half(dis*(t2@W3)); hQ = half(relu(agg32(hP)+b3)) ---
    gemm_mfma_kernel<64, 32, false, false, true><<<cdiv(N, 64), 256, 0, stream>>>(
        hQ, wt + 12288, nullptr, dis, hP, N);                         // hP = Z3
    aggregate_f16_kernel<32, 2, true, true, true><<<cdiv(N, 8), TPB, 0, stream>>>(
        hP, rowstart, rowdeg, csr, dis, b3, hQ, N);                   // hQ = t3

    // --- Layer 4: hP = half(dis*(t3@W4)); out = agg16(hP)+b4 (fp32) ---
    gemm_mfma_kernel<32, 16, false, false, true><<<cdiv(N, 64), 256, 0, stream>>>(
        hQ, wt + 14336, nullptr, dis, hP, N);                         // hP = Z4
    aggregate_f16_kernel<16, 4, true, false, false><<<cdiv(N, 16), TPB, 0, stream>>>(
        hP, rowstart, rowdeg, csr, dis, b4, out, N);
}

// Round 11
// 314.349 us; speedup vs baseline: 1.4246x; 1.0230x over previous
//
#include <hip/hip_runtime.h>

// GCN pull-mode, round 11.
// agg64 is fill-rate bound (random 128B line gathers ~3.0-3.35 TB/s TCC fill;
// MLP ample at ~176 lines/CU in flight) — structural floor, untouched.
// This round removes dispatch/streaming fat:
//  - gemm12: layers 1+2 GEMMs fused (MFMA chain -> per-wave LDS transpose ->
//    MFMA chain), kills t1 materialization (38 MB) + a dispatch.
//  - agg32+gemm4 fused: 16-row blocks, t3 in LDS, wave0 does the one
//    16x16x32 MFMA -> Z4. Kills GEMM4 dispatch + t3 round-trip.
//  - bcur zeroing folded into wprep (memset dispatch gone).
// 12 -> 9 dispatches.

#define TPB 256
#define NBUCK 782    // ceil(100000/128)
#define BCAP 3072    // fixed slot size; mean 2047, +22 sigma headroom
#define CHUNK 8192   // edges per block in scatter

typedef __attribute__((ext_vector_type(8))) _Float16 half8;
typedef __attribute__((ext_vector_type(4))) _Float16 half4;
typedef __attribute__((ext_vector_type(4))) float f32x4;

// --- Scatter packed edges into fixed bucket slots (no scan needed) ---
__global__ void bscatter_kernel(const int* __restrict__ src, const int* __restrict__ dst,
                                int* __restrict__ bcur, int* __restrict__ bsort, int E) {
    __shared__ int h[NBUCK];
    __shared__ int cur[NBUCK];
    int tid = threadIdx.x;
    for (int i = tid; i < NBUCK; i += blockDim.x) h[i] = 0;
    __syncthreads();
    int base = blockIdx.x * CHUNK;
    int lim = min(base + CHUNK, E);
    for (int e = base + tid; e < lim; e += blockDim.x)
        atomicAdd(&h[dst[e] >> 7], 1);
    __syncthreads();
    for (int i = tid; i < NBUCK; i += blockDim.x)
        cur[i] = h[i] ? (atomicAdd(&bcur[i], h[i]) + i * BCAP) : 0;
    __syncthreads();
    for (int e = base + tid; e < lim; e += blockDim.x) {
        int d = dst[e];
        int pos = atomicAdd(&cur[d >> 7], 1);
        bsort[pos] = ((d & 127) << 17) | src[e];  // src < 2^17
    }
}

// --- Per-bucket local sort -> csr slot; rowstart/rowdeg/dis; X prescale ---
__global__ __launch_bounds__(256) void bbuild_kernel(
        const int* __restrict__ bcur, const int* __restrict__ bsort,
        int* __restrict__ csr, int* __restrict__ rowstart, int* __restrict__ rowdeg,
        float* __restrict__ dis,
        const float4* __restrict__ x4, _Float16* __restrict__ xs,
        int N) {
    __shared__ int ebuf[BCAP];
    __shared__ int obuf[BCAP];
    __shared__ int cnt[128];
    __shared__ int off[129];
    __shared__ float sdis[128];
    int b = blockIdx.x;
    int tid = threadIdx.x;
    int ebase = b * BCAP;
    int n = min(bcur[b], BCAP);
    if (tid < 128) cnt[tid] = 0;
    __syncthreads();
    for (int i = tid; i < n; i += 256) {
        int p = bsort[ebase + i];
        ebuf[i] = p;
        atomicAdd(&cnt[p >> 17], 1);
    }
    __syncthreads();
    if (tid < 64) {
        int lane = tid;
        int v0 = cnt[lane];
#pragma unroll
        for (int d = 1; d < 64; d <<= 1) { int u = __shfl_up(v0, d, 64); if (lane >= d) v0 += u; }
        off[lane + 1] = v0;
        int tot0 = __shfl(v0, 63, 64);
        int v1 = cnt[64 + lane];
#pragma unroll
        for (int d = 1; d < 64; d <<= 1) { int u = __shfl_up(v1, d, 64); if (lane >= d) v1 += u; }
        off[64 + lane + 1] = tot0 + v1;
        if (lane == 0) off[0] = 0;
    }
    __syncthreads();
    int node0 = b << 7;
    if (tid < 128 && node0 + tid < N) {
        int deg = off[tid + 1] - off[tid];
        rowstart[node0 + tid] = ebase + off[tid];
        rowdeg[node0 + tid] = deg;
        float d = rsqrtf((float)deg + 1.0f);
        dis[node0 + tid] = d;
        sdis[tid] = d;
    }
    if (tid < 128) cnt[tid] = off[tid];  // reuse as cursor
    __syncthreads();
    for (int i = tid; i < n; i += 256) {
        int p = ebuf[i];
        int pos = atomicAdd(&cnt[p >> 17], 1);
        obuf[pos] = p & 0x1FFFF;
    }
    __syncthreads();
    for (int i = tid; i < n; i += 256)
        csr[ebase + i] = obuf[i];
    // fused prescale: xs[node] = half(x[node] * dis[node]) for this bucket
    for (int i = tid; i < 128 * 16; i += 256) {
        int r = i >> 4, c = i & 15;
        int node = node0 + r;
        if (node >= N) break;
        float d = sdis[r];
        float4 v = x4[(size_t)node * 16 + c];
        half4 h;
        h[0] = (_Float16)(v.x * d); h[1] = (_Float16)(v.y * d);
        h[2] = (_Float16)(v.z * d); h[3] = (_Float16)(v.w * d);
        *(half4*)(xs + (size_t)node * 64 + 4 * c) = h;
    }
}

// Transpose + fp16-convert weights (Wt[m*K+k] = half(W[k*M+m])); zero bcur.
// Sections: W1t 96x64 @0, W2t 64x96 @6144, W3t 32x64 @12288, W4t 16x32 @14336.
__global__ void wprep_kernel(const float* __restrict__ W1, const float* __restrict__ W2,
                             const float* __restrict__ W3, const float* __restrict__ W4,
                             _Float16* __restrict__ wt, int* __restrict__ bcur) {
    int t = blockIdx.x * blockDim.x + threadIdx.x;
    if (t < 788) bcur[t] = 0;
    if (t < 6144) {
        int m = t / 64, k = t % 64;
        wt[t] = (_Float16)W1[k * 96 + m];
    } else if (t < 12288) {
        int i = t - 6144; int m = i / 96, k = i % 96;
        wt[t] = (_Float16)W2[k * 64 + m];
    } else if (t < 14336) {
        int i = t - 12288; int m = i / 64, k = i % 64;
        wt[t] = (_Float16)W3[k * 32 + m];
    } else if (t < 14848) {
        int i = t - 14336; int m = i / 32, k = i % 32;
        wt[t] = (_Float16)W4[k * 16 + m];
    }
}

// Fused layers 1+2 GEMM: Z2 = dis * (relu(aggX@W1 + b1) @ W2), all fp16 I/O.
// One wave per 16-row strip. Chain1 (K=64,M=96): a-frags from global, b-frags
// from W1t, per-ct epilogue (bias+relu) -> per-wave LDS staging (C-layout ->
// A-layout transpose). Chain2 (K=96,M=64): a2 from LDS, b from W2t, *dis.
__global__ __launch_bounds__(256) void gemm12_kernel(
        const _Float16* __restrict__ X, const _Float16* __restrict__ W1t,
        const _Float16* __restrict__ W2t, const float* __restrict__ b1,
        const float* __restrict__ dis, _Float16* __restrict__ Z2, int N) {
    __shared__ _Float16 sT[4][16 * 96];
    int tid = threadIdx.x;
    int wid = tid >> 6;
    int lane = tid & 63;
    int quad = lane >> 4;
    int m16 = lane & 15;
    int wave = (blockIdx.x * blockDim.x + tid) >> 6;
    int rbase = wave * 16;
    bool active = rbase < N;
    _Float16* t1 = sT[wid];

    if (active) {
        int arow = rbase + m16;
        half8 a[2];
        if (arow < N) {
            a[0] = *(const half8*)(X + (size_t)arow * 64 + quad * 8);
            a[1] = *(const half8*)(X + (size_t)arow * 64 + 32 + quad * 8);
        } else {
#pragma unroll
            for (int j = 0; j < 8; ++j) { a[0][j] = (_Float16)0.f; a[1][j] = (_Float16)0.f; }
        }
#pragma unroll
        for (int ct = 0; ct < 6; ++ct) {
            f32x4 c = {0.f, 0.f, 0.f, 0.f};
#pragma unroll
            for (int kt = 0; kt < 2; ++kt) {
                half8 b = *(const half8*)(W1t + (size_t)(ct * 16 + m16) * 64 + kt * 32 + quad * 8);
                c = __builtin_amdgcn_mfma_f32_16x16x32_f16(a[kt], b, c, 0, 0, 0);
            }
            int col = ct * 16 + m16;
            float bb = b1[col];
#pragma unroll
            for (int r = 0; r < 4; ++r) {
                float v = fmaxf(c[r] + bb, 0.f);
                t1[(quad * 4 + r) * 96 + col] = (_Float16)v;
            }
        }
    }
    __syncthreads();
    if (active) {
        half8 a2[3];
#pragma unroll
        for (int kt = 0; kt < 3; ++kt)
            a2[kt] = *(const half8*)(t1 + m16 * 96 + kt * 32 + quad * 8);
        float dv[4];
#pragma unroll
        for (int r = 0; r < 4; ++r) {
            int orow = rbase + quad * 4 + r;
            dv[r] = (orow < N) ? dis[orow] : 0.f;
        }
#pragma unroll
        for (int ct = 0; ct < 4; ++ct) {
            f32x4 c = {0.f, 0.f, 0.f, 0.f};
#pragma unroll
            for (int kt = 0; kt < 3; ++kt) {
                half8 b = *(const half8*)(W2t + (size_t)(ct * 16 + m16) * 96 + kt * 32 + quad * 8);
                c = __builtin_amdgcn_mfma_f32_16x16x32_f16(a2[kt], b, c, 0, 0, 0);
            }
            int col = ct * 16 + m16;
#pragma unroll
            for (int r = 0; r < 4; ++r) {
                int orow = rbase + quad * 4 + r;
                if (orow < N)
                    Z2[(size_t)orow * 64 + col] = (_Float16)(c[r] * dv[r]);
            }
        }
    }
}

// MFMA f16 GEMM (layer 3): out fp16 = X fp16 @ W (*dis).
template <int K, int MF, bool RELU, bool BIAS, bool DIS>
__global__ __launch_bounds__(256) void gemm_mfma_kernel(
        const _Float16* __restrict__ X, const _Float16* __restrict__ Wt,
        const float* __restrict__ bias, const float* __restrict__ dis,
        _Float16* __restrict__ outp, int N) {
    constexpr int KT = K / 32;
    constexpr int CT = MF / 16;
    int wave = (blockIdx.x * blockDim.x + threadIdx.x) >> 6;
    int lane = threadIdx.x & 63;
    int quad = lane >> 4;
    int m16 = lane & 15;
    int rbase = wave * 16;
    if (rbase >= N) return;
    int arow = rbase + m16;

    half8 a[KT];
    if (arow < N) {
#pragma unroll
        for (int kt = 0; kt < KT; ++kt)
            a[kt] = *(const half8*)(X + (size_t)arow * K + kt * 32 + quad * 8);
    } else {
#pragma unroll
        for (int kt = 0; kt < KT; ++kt) {
#pragma unroll
            for (int j = 0; j < 8; ++j) a[kt][j] = (_Float16)0.f;
        }
    }
    float dvals[4];
    if (DIS) {
#pragma unroll
        for (int r = 0; r < 4; ++r) {
            int orow = rbase + quad * 4 + r;
            dvals[r] = (orow < N) ? dis[orow] : 0.f;
        }
    }
#pragma unroll
    for (int ct = 0; ct < CT; ++ct) {
        f32x4 c = {0.f, 0.f, 0.f, 0.f};
#pragma unroll
        for (int kt = 0; kt < KT; ++kt) {
            half8 b = *(const half8*)(Wt + (size_t)(ct * 16 + m16) * K + kt * 32 + quad * 8);
            c = __builtin_amdgcn_mfma_f32_16x16x32_f16(a[kt], b, c, 0, 0, 0);
        }
        int col = ct * 16 + m16;
        float bb = BIAS ? bias[col] : 0.f;
#pragma unroll
        for (int r = 0; r < 4; ++r) {
            int orow = rbase + quad * 4 + r;
            if (orow < N) {
                float v = c[r] + bb;
                if (RELU) v = fmaxf(v, 0.f);
                if (DIS) v *= dvals[r];
                outp[(size_t)orow * MF + col] = (_Float16)v;
            }
        }
    }
}

// Pull aggregation over fp16 messages (standalone). RPW rows per wave.
template <int F, int RPW, bool BIAS, bool RELU, bool OUTH>
__global__ void aggregate_f16_kernel(const _Float16* __restrict__ hs,
                                     const int* __restrict__ rowstart,
                                     const int* __restrict__ rowdeg,
                                     const int* __restrict__ csr,
                                     const float* __restrict__ dis,
                                     const float* __restrict__ bias,
                                     void* __restrict__ outp, int N) {
    constexpr int SPAN = 64 / RPW;
    constexpr int LPR = F / 8;
    constexpr int G = SPAN / LPR;
    int wave = (blockIdx.x * blockDim.x + threadIdx.x) >> 6;
    int lane = threadIdx.x & 63;
    int srow = lane / SPAN;
    int l2 = lane % SPAN;
    int g = l2 / LPR;
    int q = l2 % LPR;
    int row = wave * RPW + srow;
    if (row >= N) return;
    int start = rowstart[row];
    int end = start + rowdeg[row];
    float a0[8] = {}, a1[8] = {};
    if (g == 0) {  // self loop
        half8 v = *(const half8*)(hs + (size_t)row * F + 8 * q);
#pragma unroll
        for (int j = 0; j < 8; ++j) a0[j] = (float)v[j];
    }
    int e = start + g;
    for (; e + G < end; e += 2 * G) {
        int s0 = csr[e];
        int s1 = csr[e + G];
        half8 v0 = *(const half8*)(hs + (size_t)s0 * F + 8 * q);
        half8 v1 = *(const half8*)(hs + (size_t)s1 * F + 8 * q);
#pragma unroll
        for (int j = 0; j < 8; ++j) { a0[j] += (float)v0[j]; a1[j] += (float)v1[j]; }
    }
    for (; e < end; e += G) {
        int s = csr[e];
        half8 v = *(const half8*)(hs + (size_t)s * F + 8 * q);
#pragma unroll
        for (int j = 0; j < 8; ++j) a0[j] += (float)v[j];
    }
#pragma unroll
    for (int j = 0; j < 8; ++j) a0[j] += a1[j];
#pragma unroll
    for (int m = LPR; m < SPAN; m <<= 1) {
#pragma unroll
        for (int j = 0; j < 8; ++j) a0[j] += __shfl_xor(a0[j], m, 64);
    }
    if (g == 0) {
        float d = dis[row];
#pragma unroll
        for (int j = 0; j < 8; ++j) a0[j] *= d;
        if (BIAS) {
#pragma unroll
            for (int j = 0; j < 8; ++j) a0[j] += bias[8 * q + j];
        }
        if (RELU) {
#pragma unroll
            for (int j = 0; j < 8; ++j) a0[j] = fmaxf(a0[j], 0.f);
        }
        if (OUTH) {
            half8 h;
#pragma unroll
            for (int j = 0; j < 8; ++j) h[j] = (_Float16)a0[j];
            *(half8*)((_Float16*)outp + (size_t)row * F + 8 * q) = h;
        } else {
            float4 o0 = {a0[0], a0[1], a0[2], a0[3]};
            float4 o1 = {a0[4], a0[5], a0[6], a0[7]};
            *(float4*)((float*)outp + (size_t)row * F + 8 * q) = o0;
            *(float4*)((float*)outp + (size_t)row * F + 8 * q + 4) = o1;
        }
    }
}

// Fused agg32 (+b3, relu) -> t3 in LDS -> MFMA @W4t (*dis) -> Z4 fp16.
// 512 threads = 8 waves x 2 rows = 16 rows/block. N % 16 == 0 assumed for
// grid exactness; all memory ops guarded anyway.
__global__ __launch_bounds__(512) void agg32_gemm4_kernel(
        const _Float16* __restrict__ hs, const int* __restrict__ rowstart,
        const int* __restrict__ rowdeg, const int* __restrict__ csr,
        const float* __restrict__ dis, const float* __restrict__ b3,
        const _Float16* __restrict__ W4t, _Float16* __restrict__ Z4, int N) {
    __shared__ _Float16 sT[16 * 32];
    int tid = threadIdx.x;
    int wid = tid >> 6;
    int lane = tid & 63;
    int srow = lane >> 5;   // SPAN=32
    int l2 = lane & 31;
    int g = l2 >> 2;        // LPR=4, G=8
    int q = l2 & 3;
    int rbase = blockIdx.x * 16;
    int br = wid * 2 + srow;
    int row = rbase + br;

    if (row < N) {
        int start = rowstart[row];
        int end = start + rowdeg[row];
        float a0[8] = {}, a1[8] = {};
        if (g == 0) {
            half8 v = *(const half8*)(hs + (size_t)row * 32 + 8 * q);
#pragma unroll
            for (int j = 0; j < 8; ++j) a0[j] = (float)v[j];
        }
        int e = start + g;
        for (; e + 8 < end; e += 16) {
            int s0 = csr[e];
            int s1 = csr[e + 8];
            half8 v0 = *(const half8*)(hs + (size_t)s0 * 32 + 8 * q);
            half8 v1 = *(const half8*)(hs + (size_t)s1 * 32 + 8 * q);
#pragma unroll
            for (int j = 0; j < 8; ++j) { a0[j] += (float)v0[j]; a1[j] += (float)v1[j]; }
        }
        for (; e < end; e += 8) {
            int s = csr[e];
            half8 v = *(const half8*)(hs + (size_t)s * 32 + 8 * q);
#pragma unroll
            for (int j = 0; j < 8; ++j) a0[j] += (float)v[j];
        }
#pragma unroll
        for (int j = 0; j < 8; ++j) a0[j] += a1[j];
#pragma unroll
        for (int m = 4; m < 32; m <<= 1) {
#pragma unroll
            for (int j = 0; j < 8; ++j) a0[j] += __shfl_xor(a0[j], m, 64);
        }
        if (g == 0) {
            float d = dis[row];
#pragma unroll
            for (int j = 0; j < 8; ++j) {
                float v = fmaxf(a0[j] * d + b3[8 * q + j], 0.f);
                sT[br * 32 + 8 * q + j] = (_Float16)v;
            }
        }
    }
    __syncthreads();
    if (wid == 0) {
        int quad = lane >> 4, m16 = lane & 15;
        half8 a = *(const half8*)(sT + m16 * 32 + quad * 8);
        half8 b = *(const half8*)(W4t + m16 * 32 + quad * 8);
        f32x4 c = {0.f, 0.f, 0.f, 0.f};
        c = __builtin_amdgcn_mfma_f32_16x16x32_f16(a, b, c, 0, 0, 0);
#pragma unroll
        for (int r = 0; r < 4; ++r) {
            int orow = rbase + quad * 4 + r;
            if (orow < N)
                Z4[(size_t)orow * 16 + m16] = (_Float16)(c[r] * dis[orow]);
        }
    }
}

static inline int cdiv(long long a, int b) { return (int)((a + b - 1) / b); }

extern "C" void kernel_launch(void* const* d_in, const int* in_sizes, int n_in,
                              void* d_out, int out_size, void* d_ws, size_t ws_size,
                              hipStream_t stream) {
    const float* x  = (const float*)d_in[0];
    const int*   ei = (const int*)d_in[1];
    const float* W1 = (const float*)d_in[2];
    const float* b1 = (const float*)d_in[3];
    const float* W2 = (const float*)d_in[4];
    const float* b2 = (const float*)d_in[5];
    const float* W3 = (const float*)d_in[6];
    const float* b3 = (const float*)d_in[7];
    const float* W4 = (const float*)d_in[8];
    const float* b4 = (const float*)d_in[9];
    float* out = (float*)d_out;

    const int N = in_sizes[0] / 64;   // 100000
    const int E = in_sizes[1] / 2;    // 1600000
    const int* src = ei;
    const int* dst = ei + E;

    int*   bcur     = (int*)d_ws;                 // 788
    int*   rowstart = bcur + 788;                 // 100096
    int*   rowdeg   = rowstart + 100096;          // 100096
    int*   csr      = rowdeg + 100096;            // NBUCK*BCAP (padded slots)
    float* dis      = (float*)(csr + NBUCK * BCAP);  // 100096
    _Float16* hP    = (_Float16*)(dis + 100096);  // N*64 halfs
    _Float16* hQ    = hP + (size_t)N * 64;        // N*64 halfs
    _Float16* wt    = hQ + (size_t)N * 64;        // 14848 halfs (Wt fp16)
    int*   bsort    = (int*)hP;  // NBUCK*BCAP ints (9.6 MB <= hP 12.8 MB), dead before hP write

    // --- build: wprep (also zeros bcur); scatter; per-bucket sort ---
    wprep_kernel<<<cdiv(14848, TPB), TPB, 0, stream>>>(W1, W2, W3, W4, wt, bcur);
    bscatter_kernel<<<cdiv(E, CHUNK), 512, 0, stream>>>(src, dst, bcur, bsort, E);
    bbuild_kernel<<<NBUCK, 256, 0, stream>>>(bcur, bsort, csr, rowstart, rowdeg, dis,
                                             (const float4*)x, hQ, N);

    // --- Layer 1 agg: hP = agg64(hQ = half(x*dis)) ---
    aggregate_f16_kernel<64, 1, false, false, true><<<cdiv(N, 4), TPB, 0, stream>>>(
        hQ, rowstart, rowdeg, csr, dis, nullptr, hP, N);

    // --- Layers 1+2 GEMMs fused: hQ = Z2 = dis*(relu(hP@W1+b1)@W2) ---
    gemm12_kernel<<<cdiv(N, 64), 256, 0, stream>>>(hP, wt + 0, wt + 6144, b1, dis, hQ, N);

    // --- Layer 2 agg: hP = t2 = half(relu(agg64(hQ)+b2)) ---
    aggregate_f16_kernel<64, 1, true, true, true><<<cdiv(N, 4), TPB, 0, stream>>>(
        hQ, rowstart, rowdeg, csr, dis, b2, hP, N);

    // --- Layer 3 GEMM: hQ = Z3 = half(dis*(t2@W3)) ---
    gemm_mfma_kernel<64, 32, false, false, true><<<cdiv(N, 64), 256, 0, stream>>>(
        hP, wt + 12288, nullptr, dis, hQ, N);

    // --- Layer 3 agg + layer 4 GEMM fused: hP = Z4 = dis*(relu(agg32(hQ)+b3)@W4) ---
    agg32_gemm4_kernel<<<cdiv(N, 16), 512, 0, stream>>>(
        hQ, rowstart, rowdeg, csr, dis, b3, wt + 14336, hP, N);

    // --- final: out = agg16(hP) + b4 (fp32) ---
    aggregate_f16_kernel<16, 4, true, false, false><<<cdiv(N, 16), TPB, 0, stream>>>(
        hP, rowstart, rowdeg, csr, dis, b4, out, N);
}

// Round 12
// 282.075 us; speedup vs baseline: 1.5876x; 1.1144x over previous
//
#include <hip/hip_runtime.h>

// GCN pull-mode, round 12. Cost model: every aggregate is line-REQUEST bound
// (E=1.6M random line requests ~= 50us each regardless of F) -> ~200us floor
// for 4 aggregates. This round removes everything between them: all GEMMs now
// run as MFMA chains inside the aggregates' epilogues (16 rows staged in LDS,
// waves 0-1 do the MFMAs; r8's scalar-matvec trap avoided).
//   mega1: agg64(xs) -> @W1+b1,relu -> @W2,*dis -> Z2
//   mega2: agg64(Z2)+b2,relu -> @W3,*dis -> Z3
//   agg32_gemm4: agg32(Z3)+b3,relu -> @W4,*dis -> Z4
//   agg16: final +b4 -> out fp32
// 7 dispatches total.

#define TPB 256
#define NBUCK 782    // ceil(100000/128)
#define BCAP 3072    // fixed slot size; mean 2047, +22 sigma headroom
#define CHUNK 8192   // edges per block in scatter

typedef __attribute__((ext_vector_type(8))) _Float16 half8;
typedef __attribute__((ext_vector_type(4))) _Float16 half4;
typedef __attribute__((ext_vector_type(4))) float f32x4;

// --- Scatter packed edges into fixed bucket slots ---
__global__ void bscatter_kernel(const int* __restrict__ src, const int* __restrict__ dst,
                                int* __restrict__ bcur, int* __restrict__ bsort, int E) {
    __shared__ int h[NBUCK];
    __shared__ int cur[NBUCK];
    int tid = threadIdx.x;
    for (int i = tid; i < NBUCK; i += blockDim.x) h[i] = 0;
    __syncthreads();
    int base = blockIdx.x * CHUNK;
    int lim = min(base + CHUNK, E);
    for (int e = base + tid; e < lim; e += blockDim.x)
        atomicAdd(&h[dst[e] >> 7], 1);
    __syncthreads();
    for (int i = tid; i < NBUCK; i += blockDim.x)
        cur[i] = h[i] ? (atomicAdd(&bcur[i], h[i]) + i * BCAP) : 0;
    __syncthreads();
    for (int e = base + tid; e < lim; e += blockDim.x) {
        int d = dst[e];
        int pos = atomicAdd(&cur[d >> 7], 1);
        bsort[pos] = ((d & 127) << 17) | src[e];  // src < 2^17
    }
}

// --- Per-bucket local sort -> csr slot; rowstart/rowdeg/dis; X prescale ---
__global__ __launch_bounds__(256) void bbuild_kernel(
        const int* __restrict__ bcur, const int* __restrict__ bsort,
        int* __restrict__ csr, int* __restrict__ rowstart, int* __restrict__ rowdeg,
        float* __restrict__ dis,
        const float4* __restrict__ x4, _Float16* __restrict__ xs,
        int N) {
    __shared__ int ebuf[BCAP];
    __shared__ int obuf[BCAP];
    __shared__ int cnt[128];
    __shared__ int off[129];
    __shared__ float sdis[128];
    int b = blockIdx.x;
    int tid = threadIdx.x;
    int ebase = b * BCAP;
    int n = min(bcur[b], BCAP);
    if (tid < 128) cnt[tid] = 0;
    __syncthreads();
    for (int i = tid; i < n; i += 256) {
        int p = bsort[ebase + i];
        ebuf[i] = p;
        atomicAdd(&cnt[p >> 17], 1);
    }
    __syncthreads();
    if (tid < 64) {
        int lane = tid;
        int v0 = cnt[lane];
#pragma unroll
        for (int d = 1; d < 64; d <<= 1) { int u = __shfl_up(v0, d, 64); if (lane >= d) v0 += u; }
        off[lane + 1] = v0;
        int tot0 = __shfl(v0, 63, 64);
        int v1 = cnt[64 + lane];
#pragma unroll
        for (int d = 1; d < 64; d <<= 1) { int u = __shfl_up(v1, d, 64); if (lane >= d) v1 += u; }
        off[64 + lane + 1] = tot0 + v1;
        if (lane == 0) off[0] = 0;
    }
    __syncthreads();
    int node0 = b << 7;
    if (tid < 128 && node0 + tid < N) {
        int deg = off[tid + 1] - off[tid];
        rowstart[node0 + tid] = ebase + off[tid];
        rowdeg[node0 + tid] = deg;
        float d = rsqrtf((float)deg + 1.0f);
        dis[node0 + tid] = d;
        sdis[tid] = d;
    }
    if (tid < 128) cnt[tid] = off[tid];  // reuse as cursor
    __syncthreads();
    for (int i = tid; i < n; i += 256) {
        int p = ebuf[i];
        int pos = atomicAdd(&cnt[p >> 17], 1);
        obuf[pos] = p & 0x1FFFF;
    }
    __syncthreads();
    for (int i = tid; i < n; i += 256)
        csr[ebase + i] = obuf[i];
    // fused prescale: xs[node] = half(x[node] * dis[node]) for this bucket
    for (int i = tid; i < 128 * 16; i += 256) {
        int r = i >> 4, c = i & 15;
        int node = node0 + r;
        if (node >= N) break;
        float d = sdis[r];
        float4 v = x4[(size_t)node * 16 + c];
        half4 h;
        h[0] = (_Float16)(v.x * d); h[1] = (_Float16)(v.y * d);
        h[2] = (_Float16)(v.z * d); h[3] = (_Float16)(v.w * d);
        *(half4*)(xs + (size_t)node * 64 + 4 * c) = h;
    }
}

// Transpose + fp16-convert weights (Wt[m*K+k] = half(W[k*M+m])); zero bcur.
// Sections: W1t 96x64 @0, W2t 64x96 @6144, W3t 32x64 @12288, W4t 16x32 @14336.
__global__ void wprep_kernel(const float* __restrict__ W1, const float* __restrict__ W2,
                             const float* __restrict__ W3, const float* __restrict__ W4,
                             _Float16* __restrict__ wt, int* __restrict__ bcur) {
    int t = blockIdx.x * blockDim.x + threadIdx.x;
    if (t < 788) bcur[t] = 0;
    if (t < 6144) {
        int m = t / 64, k = t % 64;
        wt[t] = (_Float16)W1[k * 96 + m];
    } else if (t < 12288) {
        int i = t - 6144; int m = i / 96, k = i % 96;
        wt[t] = (_Float16)W2[k * 64 + m];
    } else if (t < 14336) {
        int i = t - 12288; int m = i / 64, k = i % 64;
        wt[t] = (_Float16)W3[k * 32 + m];
    } else if (t < 14848) {
        int i = t - 14336; int m = i / 32, k = i % 32;
        wt[t] = (_Float16)W4[k * 16 + m];
    }
}

// mega1: 16 rows/block (8 waves x 2 rows). agg64(xs)*dis -> sAgg fp16 ->
// waves 0-1: MFMA @W1 (+b1, relu) -> sT fp16 -> MFMA @W2 (*dis) -> Z2 fp16.
__global__ __launch_bounds__(512) void mega1_kernel(
        const _Float16* __restrict__ hs, const int* __restrict__ rowstart,
        const int* __restrict__ rowdeg, const int* __restrict__ csr,
        const float* __restrict__ dis,
        const _Float16* __restrict__ W1t, const float* __restrict__ b1,
        const _Float16* __restrict__ W2t,
        _Float16* __restrict__ Z2, int N) {
    __shared__ _Float16 sAgg[16 * 64];
    __shared__ _Float16 sT[16 * 96];
    int tid = threadIdx.x;
    int wid = tid >> 6;
    int lane = tid & 63;
    int srow = lane >> 5;    // RPW=2: SPAN=32
    int l2 = lane & 31;
    int g = l2 >> 3;         // LPR=8, G=4
    int q = l2 & 7;
    int rbase = blockIdx.x * 16;
    int br = wid * 2 + srow;
    int row = rbase + br;

    if (row < N) {
        int start = rowstart[row];
        int end = start + rowdeg[row];
        float a0[8] = {}, a1[8] = {};
        if (g == 0) {  // self loop
            half8 v = *(const half8*)(hs + (size_t)row * 64 + 8 * q);
#pragma unroll
            for (int j = 0; j < 8; ++j) a0[j] = (float)v[j];
        }
        int e = start + g;
        for (; e + 4 < end; e += 8) {
            int s0 = csr[e];
            int s1 = csr[e + 4];
            half8 v0 = *(const half8*)(hs + (size_t)s0 * 64 + 8 * q);
            half8 v1 = *(const half8*)(hs + (size_t)s1 * 64 + 8 * q);
#pragma unroll
            for (int j = 0; j < 8; ++j) { a0[j] += (float)v0[j]; a1[j] += (float)v1[j]; }
        }
        for (; e < end; e += 4) {
            int s = csr[e];
            half8 v = *(const half8*)(hs + (size_t)s * 64 + 8 * q);
#pragma unroll
            for (int j = 0; j < 8; ++j) a0[j] += (float)v[j];
        }
#pragma unroll
        for (int j = 0; j < 8; ++j) a0[j] += a1[j];
#pragma unroll
        for (int m = 8; m < 32; m <<= 1) {
#pragma unroll
            for (int j = 0; j < 8; ++j) a0[j] += __shfl_xor(a0[j], m, 64);
        }
        if (g == 0) {
            float d = dis[row];
#pragma unroll
            for (int j = 0; j < 8; ++j)
                sAgg[br * 64 + 8 * q + j] = (_Float16)(a0[j] * d);
        }
    }
    __syncthreads();
    int quad = lane >> 4, m16 = lane & 15;
    if (wid < 2) {
        // chain1: aggX(16x64) @ W1 (64->96), +b1, relu -> sT
        half8 a[2];
        a[0] = *(const half8*)(sAgg + m16 * 64 + quad * 8);
        a[1] = *(const half8*)(sAgg + m16 * 64 + 32 + quad * 8);
#pragma unroll
        for (int i = 0; i < 3; ++i) {
            int ct = wid * 3 + i;
            f32x4 c = {0.f, 0.f, 0.f, 0.f};
#pragma unroll
            for (int kt = 0; kt < 2; ++kt) {
                half8 b = *(const half8*)(W1t + (size_t)(ct * 16 + m16) * 64 + kt * 32 + quad * 8);
                c = __builtin_amdgcn_mfma_f32_16x16x32_f16(a[kt], b, c, 0, 0, 0);
            }
            int col = ct * 16 + m16;
            float bb = b1[col];
#pragma unroll
            for (int r = 0; r < 4; ++r)
                sT[(quad * 4 + r) * 96 + col] = (_Float16)fmaxf(c[r] + bb, 0.f);
        }
    }
    __syncthreads();
    if (wid < 2) {
        // chain2: t1(16x96) @ W2 (96->64), *dis -> Z2
        half8 a2[3];
#pragma unroll
        for (int kt = 0; kt < 3; ++kt)
            a2[kt] = *(const half8*)(sT + m16 * 96 + kt * 32 + quad * 8);
        float dv[4];
#pragma unroll
        for (int r = 0; r < 4; ++r) {
            int orow = rbase + quad * 4 + r;
            dv[r] = (orow < N) ? dis[orow] : 0.f;
        }
#pragma unroll
        for (int i = 0; i < 2; ++i) {
            int ct = wid * 2 + i;
            f32x4 c = {0.f, 0.f, 0.f, 0.f};
#pragma unroll
            for (int kt = 0; kt < 3; ++kt) {
                half8 b = *(const half8*)(W2t + (size_t)(ct * 16 + m16) * 96 + kt * 32 + quad * 8);
                c = __builtin_amdgcn_mfma_f32_16x16x32_f16(a2[kt], b, c, 0, 0, 0);
            }
            int col = ct * 16 + m16;
#pragma unroll
            for (int r = 0; r < 4; ++r) {
                int orow = rbase + quad * 4 + r;
                if (orow < N)
                    Z2[(size_t)orow * 64 + col] = (_Float16)(c[r] * dv[r]);
            }
        }
    }
}

// mega2: agg64(Z2), t2 = relu(dis*sum + b2) -> sAgg fp16 ->
// waves 0-1: MFMA @W3 (*dis) -> Z3 fp16 (32 wide).
__global__ __launch_bounds__(512) void mega2_kernel(
        const _Float16* __restrict__ hs, const int* __restrict__ rowstart,
        const int* __restrict__ rowdeg, const int* __restrict__ csr,
        const float* __restrict__ dis, const float* __restrict__ b2,
        const _Float16* __restrict__ W3t,
        _Float16* __restrict__ Z3, int N) {
    __shared__ _Float16 sAgg[16 * 64];
    int tid = threadIdx.x;
    int wid = tid >> 6;
    int lane = tid & 63;
    int srow = lane >> 5;
    int l2 = lane & 31;
    int g = l2 >> 3;
    int q = l2 & 7;
    int rbase = blockIdx.x * 16;
    int br = wid * 2 + srow;
    int row = rbase + br;

    if (row < N) {
        int start = rowstart[row];
        int end = start + rowdeg[row];
        float a0[8] = {}, a1[8] = {};
        if (g == 0) {
            half8 v = *(const half8*)(hs + (size_t)row * 64 + 8 * q);
#pragma unroll
            for (int j = 0; j < 8; ++j) a0[j] = (float)v[j];
        }
        int e = start + g;
        for (; e + 4 < end; e += 8) {
            int s0 = csr[e];
            int s1 = csr[e + 4];
            half8 v0 = *(const half8*)(hs + (size_t)s0 * 64 + 8 * q);
            half8 v1 = *(const half8*)(hs + (size_t)s1 * 64 + 8 * q);
#pragma unroll
            for (int j = 0; j < 8; ++j) { a0[j] += (float)v0[j]; a1[j] += (float)v1[j]; }
        }
        for (; e < end; e += 4) {
            int s = csr[e];
            half8 v = *(const half8*)(hs + (size_t)s * 64 + 8 * q);
#pragma unroll
            for (int j = 0; j < 8; ++j) a0[j] += (float)v[j];
        }
#pragma unroll
        for (int j = 0; j < 8; ++j) a0[j] += a1[j];
#pragma unroll
        for (int m = 8; m < 32; m <<= 1) {
#pragma unroll
            for (int j = 0; j < 8; ++j) a0[j] += __shfl_xor(a0[j], m, 64);
        }
        if (g == 0) {
            float d = dis[row];
#pragma unroll
            for (int j = 0; j < 8; ++j) {
                float v = fmaxf(a0[j] * d + b2[8 * q + j], 0.f);
                sAgg[br * 64 + 8 * q + j] = (_Float16)v;
            }
        }
    }
    __syncthreads();
    if (wid < 2) {
        int quad = lane >> 4, m16 = lane & 15;
        half8 a[2];
        a[0] = *(const half8*)(sAgg + m16 * 64 + quad * 8);
        a[1] = *(const half8*)(sAgg + m16 * 64 + 32 + quad * 8);
        int ct = wid;  // 2 col tiles total
        f32x4 c = {0.f, 0.f, 0.f, 0.f};
#pragma unroll
        for (int kt = 0; kt < 2; ++kt) {
            half8 b = *(const half8*)(W3t + (size_t)(ct * 16 + m16) * 64 + kt * 32 + quad * 8);
            c = __builtin_amdgcn_mfma_f32_16x16x32_f16(a[kt], b, c, 0, 0, 0);
        }
        int col = ct * 16 + m16;
#pragma unroll
        for (int r = 0; r < 4; ++r) {
            int orow = rbase + quad * 4 + r;
            if (orow < N)
                Z3[(size_t)orow * 32 + col] = (_Float16)(c[r] * dis[orow]);
        }
    }
}

// Fused agg32 (+b3, relu) -> t3 in LDS -> MFMA @W4t (*dis) -> Z4 fp16.
__global__ __launch_bounds__(512) void agg32_gemm4_kernel(
        const _Float16* __restrict__ hs, const int* __restrict__ rowstart,
        const int* __restrict__ rowdeg, const int* __restrict__ csr,
        const float* __restrict__ dis, const float* __restrict__ b3,
        const _Float16* __restrict__ W4t, _Float16* __restrict__ Z4, int N) {
    __shared__ _Float16 sT[16 * 32];
    int tid = threadIdx.x;
    int wid = tid >> 6;
    int lane = tid & 63;
    int srow = lane >> 5;   // SPAN=32
    int l2 = lane & 31;
    int g = l2 >> 2;        // LPR=4, G=8
    int q = l2 & 3;
    int rbase = blockIdx.x * 16;
    int br = wid * 2 + srow;
    int row = rbase + br;

    if (row < N) {
        int start = rowstart[row];
        int end = start + rowdeg[row];
        float a0[8] = {}, a1[8] = {};
        if (g == 0) {
            half8 v = *(const half8*)(hs + (size_t)row * 32 + 8 * q);
#pragma unroll
            for (int j = 0; j < 8; ++j) a0[j] = (float)v[j];
        }
        int e = start + g;
        for (; e + 8 < end; e += 16) {
            int s0 = csr[e];
            int s1 = csr[e + 8];
            half8 v0 = *(const half8*)(hs + (size_t)s0 * 32 + 8 * q);
            half8 v1 = *(const half8*)(hs + (size_t)s1 * 32 + 8 * q);
#pragma unroll
            for (int j = 0; j < 8; ++j) { a0[j] += (float)v0[j]; a1[j] += (float)v1[j]; }
        }
        for (; e < end; e += 8) {
            int s = csr[e];
            half8 v = *(const half8*)(hs + (size_t)s * 32 + 8 * q);
#pragma unroll
            for (int j = 0; j < 8; ++j) a0[j] += (float)v[j];
        }
#pragma unroll
        for (int j = 0; j < 8; ++j) a0[j] += a1[j];
#pragma unroll
        for (int m = 4; m < 32; m <<= 1) {
#pragma unroll
            for (int j = 0; j < 8; ++j) a0[j] += __shfl_xor(a0[j], m, 64);
        }
        if (g == 0) {
            float d = dis[row];
#pragma unroll
            for (int j = 0; j < 8; ++j) {
                float v = fmaxf(a0[j] * d + b3[8 * q + j], 0.f);
                sT[br * 32 + 8 * q + j] = (_Float16)v;
            }
        }
    }
    __syncthreads();
    if (wid == 0) {
        int quad = lane >> 4, m16 = lane & 15;
        half8 a = *(const half8*)(sT + m16 * 32 + quad * 8);
        half8 b = *(const half8*)(W4t + m16 * 32 + quad * 8);
        f32x4 c = {0.f, 0.f, 0.f, 0.f};
        c = __builtin_amdgcn_mfma_f32_16x16x32_f16(a, b, c, 0, 0, 0);
#pragma unroll
        for (int r = 0; r < 4; ++r) {
            int orow = rbase + quad * 4 + r;
            if (orow < N)
                Z4[(size_t)orow * 16 + m16] = (_Float16)(c[r] * dis[orow]);
        }
    }
}

// Final pull aggregation (F=16, RPW=4): out(fp32) = dis*sum + b4.
__global__ void aggregate_final_kernel(const _Float16* __restrict__ hs,
                                       const int* __restrict__ rowstart,
                                       const int* __restrict__ rowdeg,
                                       const int* __restrict__ csr,
                                       const float* __restrict__ dis,
                                       const float* __restrict__ bias,
                                       float* __restrict__ outp, int N) {
    constexpr int SPAN = 16, LPR = 2, G = 8;
    int wave = (blockIdx.x * blockDim.x + threadIdx.x) >> 6;
    int lane = threadIdx.x & 63;
    int srow = lane / SPAN;
    int l2 = lane % SPAN;
    int g = l2 / LPR;
    int q = l2 % LPR;
    int row = wave * 4 + srow;
    if (row >= N) return;
    int start = rowstart[row];
    int end = start + rowdeg[row];
    float a0[8] = {}, a1[8] = {};
    if (g == 0) {
        half8 v = *(const half8*)(hs + (size_t)row * 16 + 8 * q);
#pragma unroll
        for (int j = 0; j < 8; ++j) a0[j] = (float)v[j];
    }
    int e = start + g;
    for (; e + G < end; e += 2 * G) {
        int s0 = csr[e];
        int s1 = csr[e + G];
        half8 v0 = *(const half8*)(hs + (size_t)s0 * 16 + 8 * q);
        half8 v1 = *(const half8*)(hs + (size_t)s1 * 16 + 8 * q);
#pragma unroll
        for (int j = 0; j < 8; ++j) { a0[j] += (float)v0[j]; a1[j] += (float)v1[j]; }
    }
    for (; e < end; e += G) {
        int s = csr[e];
        half8 v = *(const half8*)(hs + (size_t)s * 16 + 8 * q);
#pragma unroll
        for (int j = 0; j < 8; ++j) a0[j] += (float)v[j];
    }
#pragma unroll
    for (int j = 0; j < 8; ++j) a0[j] += a1[j];
#pragma unroll
    for (int m = LPR; m < SPAN; m <<= 1) {
#pragma unroll
        for (int j = 0; j < 8; ++j) a0[j] += __shfl_xor(a0[j], m, 64);
    }
    if (g == 0) {
        float d = dis[row];
        float4 o0, o1;
        o0.x = a0[0] * d + bias[8 * q + 0];
        o0.y = a0[1] * d + bias[8 * q + 1];
        o0.z = a0[2] * d + bias[8 * q + 2];
        o0.w = a0[3] * d + bias[8 * q + 3];
        o1.x = a0[4] * d + bias[8 * q + 4];
        o1.y = a0[5] * d + bias[8 * q + 5];
        o1.z = a0[6] * d + bias[8 * q + 6];
        o1.w = a0[7] * d + bias[8 * q + 7];
        *(float4*)(outp + (size_t)row * 16 + 8 * q) = o0;
        *(float4*)(outp + (size_t)row * 16 + 8 * q + 4) = o1;
    }
}

static inline int cdiv(long long a, int b) { return (int)((a + b - 1) / b); }

extern "C" void kernel_launch(void* const* d_in, const int* in_sizes, int n_in,
                              void* d_out, int out_size, void* d_ws, size_t ws_size,
                              hipStream_t stream) {
    const float* x  = (const float*)d_in[0];
    const int*   ei = (const int*)d_in[1];
    const float* W1 = (const float*)d_in[2];
    const float* b1 = (const float*)d_in[3];
    const float* W2 = (const float*)d_in[4];
    const float* b2 = (const float*)d_in[5];
    const float* W3 = (const float*)d_in[6];
    const float* b3 = (const float*)d_in[7];
    const float* W4 = (const float*)d_in[8];
    const float* b4 = (const float*)d_in[9];
    float* out = (float*)d_out;

    const int N = in_sizes[0] / 64;   // 100000
    const int E = in_sizes[1] / 2;    // 1600000
    const int* src = ei;
    const int* dst = ei + E;

    int*   bcur     = (int*)d_ws;                 // 788
    int*   rowstart = bcur + 788;                 // 100096
    int*   rowdeg   = rowstart + 100096;          // 100096
    int*   csr      = rowdeg + 100096;            // NBUCK*BCAP (padded slots)
    float* dis      = (float*)(csr + NBUCK * BCAP);  // 100096
    _Float16* hP    = (_Float16*)(dis + 100096);  // N*64 halfs
    _Float16* hQ    = hP + (size_t)N * 64;        // N*64 halfs
    _Float16* wt    = hQ + (size_t)N * 64;        // 14848 halfs (Wt fp16)
    int*   bsort    = (int*)hP;  // NBUCK*BCAP ints, dead before hP's first write

    // --- build: wprep (zeros bcur + converts weights); scatter; bucket sort ---
    wprep_kernel<<<cdiv(14848, TPB), TPB, 0, stream>>>(W1, W2, W3, W4, wt, bcur);
    bscatter_kernel<<<cdiv(E, CHUNK), 512, 0, stream>>>(src, dst, bcur, bsort, E);
    bbuild_kernel<<<NBUCK, 256, 0, stream>>>(bcur, bsort, csr, rowstart, rowdeg, dis,
                                             (const float4*)x, hQ, N);

    // --- mega1: hP = Z2 = dis*(relu(agg64(hQ)@W1+b1)@W2) ---
    mega1_kernel<<<cdiv(N, 16), 512, 0, stream>>>(
        hQ, rowstart, rowdeg, csr, dis, wt + 0, b1, wt + 6144, hP, N);

    // --- mega2: hQ = Z3 = dis*(relu(agg64(hP)+b2)@W3) ---
    mega2_kernel<<<cdiv(N, 16), 512, 0, stream>>>(
        hP, rowstart, rowdeg, csr, dis, b2, wt + 12288, hQ, N);

    // --- agg32+gemm4: hP = Z4 = dis*(relu(agg32(hQ)+b3)@W4) ---
    agg32_gemm4_kernel<<<cdiv(N, 16), 512, 0, stream>>>(
        hQ, rowstart, rowdeg, csr, dis, b3, wt + 14336, hP, N);

    // --- final: out = agg16(hP) + b4 (fp32) ---
    aggregate_final_kernel<<<cdiv(N, 16), TPB, 0, stream>>>(
        hP, rowstart, rowdeg, csr, dis, b4, out, N);
}